// Round 1
// baseline (1682.622 us; speedup 1.0000x reference)
//
#include <hip/hip_runtime.h>

#define L_ 2048
#define NROW 16384
#define FIN 1038

// ---------------- node embedding: hV = node_features @ W_node + b ----------------
__global__ __launch_bounds__(256) void k_node(const float* __restrict__ X,
                                              const float* __restrict__ W,
                                              const float* __restrict__ bias,
                                              float* __restrict__ out) {
  __shared__ float As[64][16];
  __shared__ float Ws[16][64];
  const int t = threadIdx.x;
  const int row0 = blockIdx.x * 64;
  const int c = t & 63, rg = t >> 6;
  float acc[16];
#pragma unroll
  for (int u = 0; u < 16; u++) acc[u] = 0.f;
  for (int kc = 0; kc < FIN; kc += 16) {
    const int kk = (FIN - kc < 16) ? (FIN - kc) : 16;
    __syncthreads();
#pragma unroll
    for (int q = 0; q < 4; q++) {
      int i = t + 256 * q;
      int r = i >> 4, cc = i & 15;
      As[r][cc] = (cc < kk) ? X[(size_t)(row0 + r) * FIN + kc + cc] : 0.f;
      int s = i >> 6, c2 = i & 63;
      Ws[s][c2] = (s < kk) ? W[(size_t)(kc + s) * 64 + c2] : 0.f;
    }
    __syncthreads();
#pragma unroll
    for (int s0 = 0; s0 < 16; s0 += 4) {
      float w0 = Ws[s0][c], w1 = Ws[s0 + 1][c], w2 = Ws[s0 + 2][c], w3 = Ws[s0 + 3][c];
#pragma unroll
      for (int u = 0; u < 16; u++) {
        const float4 a = *(const float4*)&As[rg + 4 * u][s0];
        acc[u] += a.x * w0 + a.y * w1 + a.z * w2 + a.w * w3;
      }
    }
  }
  const float bb = bias[c];
#pragma unroll
  for (int u = 0; u < 16; u++)
    out[(size_t)(row0 + rg + 4 * u) * 64 + c] = acc[u] + bb;
}

// ---------------- edges: distances + top-30 selection ----------------
__global__ __launch_bounds__(256) void k_edges(const float* __restrict__ coords,
                                               const float* __restrict__ mask,
                                               int* __restrict__ Eidx,
                                               float* __restrict__ Dnb) {
  const int row = blockIdx.x;
  const int b = row >> 11;
  const int t = threadIdx.x;
  const int lane = t & 63, wid = t >> 6;
  __shared__ float sred[4];
  __shared__ unsigned long long skey[4];
  __shared__ unsigned long long swin;
  const float* cb = coords + (size_t)b * L_ * 3;
  const int i = row & (L_ - 1);
  const float cix = cb[i * 3 + 0], ciy = cb[i * 3 + 1], ciz = cb[i * 3 + 2];
  const float mi = mask[row];
  const float* mb = mask + (size_t)b * L_;
  float d[8], mj[8];
  float dmax = 0.f;
#pragma unroll
  for (int u = 0; u < 8; u++) {
    int j = t + 256 * u;
    float dx = cix - cb[j * 3 + 0];
    float dy = ciy - cb[j * 3 + 1];
    float dz = ciz - cb[j * 3 + 2];
    float dist = sqrtf(dx * dx + dy * dy + dz * dz + 1e-6f);
    d[u] = dist;
    mj[u] = mb[j];
    dmax = fmaxf(dmax, dist);
  }
#pragma unroll
  for (int off = 32; off; off >>= 1) dmax = fmaxf(dmax, __shfl_xor(dmax, off, 64));
  if (lane == 0) sred[wid] = dmax;
  __syncthreads();
  dmax = fmaxf(fmaxf(sred[0], sred[1]), fmaxf(sred[2], sred[3]));
  unsigned long long key[8];
#pragma unroll
  for (int u = 0; u < 8; u++) {
    int j = t + 256 * u;
    float adj = d[u] + (1.f - mi * mj[u]) * dmax;
    key[u] = ((unsigned long long)__float_as_uint(adj) << 32) | (unsigned int)j;
  }
  for (int r = 0; r < 30; r++) {
    unsigned long long k = key[0];
#pragma unroll
    for (int u = 1; u < 8; u++) k = (key[u] < k) ? key[u] : k;
#pragma unroll
    for (int off = 32; off; off >>= 1) {
      unsigned long long o = __shfl_xor(k, off, 64);
      k = (o < k) ? o : k;
    }
    if (lane == 0) skey[wid] = k;
    __syncthreads();
    if (t == 0) {
      unsigned long long w01 = skey[0] < skey[1] ? skey[0] : skey[1];
      unsigned long long w23 = skey[2] < skey[3] ? skey[2] : skey[3];
      unsigned long long w = w01 < w23 ? w01 : w23;
      swin = w;
      Eidx[(size_t)row * 30 + r] = (int)(w & 0xffffffffull);
      Dnb[(size_t)row * 30 + r] = __uint_as_float((unsigned int)(w >> 32));
    }
    __syncthreads();
    unsigned long long w = swin;
    int j = (int)(w & 0xffffffffull);
    if ((j & 255) == t) key[j >> 8] = ~0ull;
  }
}

// ---------------- generic 64x64 GEMM + bias (Q projection) ----------------
__global__ __launch_bounds__(256) void k_gemm64(const float* __restrict__ X,
                                                const float* __restrict__ W,
                                                const float* __restrict__ bias,
                                                float* __restrict__ out) {
  __shared__ float Xs[64][64];
  __shared__ float Ws[64][64];
  const int t = threadIdx.x;
  const int row0 = blockIdx.x * 64;
#pragma unroll
  for (int q = 0; q < 16; q++) {
    int i = t + 256 * q;
    int r = i >> 6, c = i & 63;
    Xs[r][c] = X[(size_t)(row0 + r) * 64 + c];
    Ws[r][c] = W[i];
  }
  __syncthreads();
  const int c = t & 63, rg = t >> 6;
  float acc[16];
#pragma unroll
  for (int u = 0; u < 16; u++) acc[u] = 0.f;
#pragma unroll
  for (int s0 = 0; s0 < 64; s0 += 4) {
    float w0 = Ws[s0][c], w1 = Ws[s0 + 1][c], w2 = Ws[s0 + 2][c], w3 = Ws[s0 + 3][c];
#pragma unroll
    for (int u = 0; u < 16; u++) {
      const float4 a = *(const float4*)&Xs[rg + 4 * u][s0];
      acc[u] += a.x * w0 + a.y * w1 + a.z * w2 + a.w * w3;
    }
  }
  const float bb = bias[c];
#pragma unroll
  for (int u = 0; u < 16; u++)
    out[(size_t)(row0 + rg + 4 * u) * 64 + c] = acc[u] + bb;
}

// ---------------- qw[row][s][h] = sum_d Q[row][h*16+d] * WK[s][h*16+d]; qbK = Q.bK ----------------
__global__ __launch_bounds__(256) void k_qw(const float* __restrict__ Q,
                                            const float* __restrict__ WK,
                                            const float* __restrict__ bK,
                                            float* __restrict__ QW,
                                            float* __restrict__ qbK) {
  __shared__ float sQ[64][64];
  __shared__ float sWK[128][64];
  const int t = threadIdx.x;
  const int row0 = blockIdx.x * 64;
#pragma unroll
  for (int q = 0; q < 16; q++) {
    int i = t + 256 * q;
    sQ[i >> 6][i & 63] = Q[(size_t)(row0 + (i >> 6)) * 64 + (i & 63)];
  }
#pragma unroll
  for (int q = 0; q < 32; q++) {
    int i = t + 256 * q;
    sWK[i >> 6][i & 63] = WK[i];
  }
  __syncthreads();
  {
    int r = t >> 2, hh = t & 3;
    float a = 0.f;
#pragma unroll
    for (int d = 0; d < 16; d++) a += sQ[r][hh * 16 + d] * bK[hh * 16 + d];
    qbK[(size_t)(row0 + r) * 4 + hh] = a;
  }
  const int h = t & 3, s2 = t >> 2;
  for (int r = 0; r < 64; r++) {
    float a0 = 0.f, a1 = 0.f;
#pragma unroll
    for (int d0 = 0; d0 < 16; d0 += 4) {
      const float4 q4 = *(const float4*)&sQ[r][h * 16 + d0];
      const float4 wa = *(const float4*)&sWK[s2][h * 16 + d0];
      const float4 wb = *(const float4*)&sWK[s2 + 64][h * 16 + d0];
      a0 += q4.x * wa.x + q4.y * wa.y + q4.z * wa.z + q4.w * wa.w;
      a1 += q4.x * wb.x + q4.y * wb.y + q4.z * wb.z + q4.w * wb.w;
    }
    QW[(size_t)(row0 + r) * 512 + s2 * 4 + h] = a0;
    QW[(size_t)(row0 + r) * 512 + (s2 + 64) * 4 + h] = a1;
  }
}

// ---------------- per-row attention core: rebuild h_E, gather, logits, softmax, P ----------------
__global__ __launch_bounds__(256) void k_attn(
    const float* __restrict__ Dnb, const int* __restrict__ Eidx,
    const float* __restrict__ hV, const float* __restrict__ mask,
    const float* __restrict__ QWg, const float* __restrict__ qbKg,
    const float* __restrict__ Wee, const float* __restrict__ geln,
    const float* __restrict__ beln, const float* __restrict__ Wep,
    const float* __restrict__ bep,
    float* __restrict__ Pg, float* __restrict__ attsum) {
  const int row = blockIdx.x;
  const int b = row >> 11;
  const int t = threadIdx.x;
  __shared__ float sEV[30][132];
  __shared__ float sQW[4][128];
  __shared__ float sRBF[30][16];
  __shared__ float sE[30][16];
  __shared__ float sWee[16][16];
  __shared__ float sWep[16][64];
  __shared__ float sbep[64];
  __shared__ float sg[16], sb[16];
  __shared__ float sqb[4];
  __shared__ float slog[4][30];
  __shared__ float satt[4][30];
  __shared__ float smk[30];
  __shared__ int sIdx[30];

  sWee[t >> 4][t & 15] = Wee[t];
  if (t < 64) sbep[t] = bep[t];
  for (int q = t; q < 1024; q += 256) sWep[q >> 6][q & 63] = Wep[q];
  if (t < 16) { sg[t] = geln[t]; sb[t] = beln[t]; }
  if (t < 4) sqb[t] = qbKg[(size_t)row * 4 + t];
  if (t < 30) {
    int j = Eidx[(size_t)row * 30 + t];
    sIdx[t] = j;
    smk[t] = mask[(b << 11) + j] * mask[row];
  }
#pragma unroll
  for (int q = 0; q < 2; q++) {
    int o = t + 256 * q;
    float v = QWg[(size_t)row * 512 + o];
    sQW[o & 3][o >> 2] = v;
  }
  __syncthreads();
  // rbf
  if (t < 30) {
    float dval = Dnb[(size_t)row * 30 + t];
#pragma unroll
    for (int r = 0; r < 16; r++) {
      float mu = 2.0f + (4.0f / 3.0f) * (float)r;
      float z = (dval - mu) * 0.8f;
      sRBF[t][r] = __expf(-z * z);
    }
  }
  __syncthreads();
  // E0 = rbf @ Wee
#pragma unroll
  for (int q = 0; q < 2; q++) {
    int o = t + 256 * q;
    if (o < 480) {
      int k = o >> 4, c = o & 15;
      float a = 0.f;
#pragma unroll
      for (int s = 0; s < 16; s++) a += sRBF[k][s] * sWee[s][c];
      sE[k][c] = a;
    }
  }
  __syncthreads();
  // LayerNorm over 16
  if (t < 30) {
    float m = 0.f;
#pragma unroll
    for (int s = 0; s < 16; s++) m += sE[t][s];
    m *= (1.f / 16.f);
    float v = 0.f;
#pragma unroll
    for (int s = 0; s < 16; s++) { float dv = sE[t][s] - m; v += dv * dv; }
    v *= (1.f / 16.f);
    float inv = rsqrtf(v + 1e-5f);
#pragma unroll
    for (int s = 0; s < 16; s++) sE[t][s] = (sE[t][s] - m) * inv * sg[s] + sb[s];
  }
  __syncthreads();
  // hEV: edge half (E @ Wep + bep) and gathered hV half
#pragma unroll
  for (int q = 0; q < 8; q++) {
    int o = t + 256 * q;
    if (o < 1920) {
      int k = o >> 6, c = o & 63;
      float a = sbep[c];
#pragma unroll
      for (int s = 0; s < 16; s++) a += sE[k][s] * sWep[s][c];
      sEV[k][c] = a;
      sEV[k][64 + c] = hV[((size_t)(b << 11) + sIdx[k]) * 64 + c];
    }
  }
  __syncthreads();
  // logits
  if (t < 120) {
    int k = t >> 2, h = t & 3;
    float a = 0.f;
#pragma unroll
    for (int s0 = 0; s0 < 128; s0 += 4) {
      const float4 e = *(const float4*)&sEV[k][s0];
      const float4 w = *(const float4*)&sQW[h][s0];
      a += e.x * w.x + e.y * w.y + e.z * w.z + e.w * w.w;
    }
    float lg = (a + sqb[h]) * 0.25f;
    if (!(smk[k] > 0.f)) lg = -3.402823466e38f;
    slog[h][k] = lg;
  }
  __syncthreads();
  // softmax (serial per head)
  if (t < 4) {
    const int h = t;
    float mx = -3.402823466e38f;
    for (int k = 0; k < 30; k++) mx = fmaxf(mx, slog[h][k]);
    float den = 0.f;
    for (int k = 0; k < 30; k++) den += __expf(slog[h][k] - mx);
    float inv = 1.f / den;
    float ss = 0.f;
    for (int k = 0; k < 30; k++) {
      float av = __expf(slog[h][k] - mx) * inv * smk[k];
      satt[h][k] = av;
      ss += av;
    }
    attsum[(size_t)row * 4 + h] = ss;
  }
  __syncthreads();
  // P[row][h*128+s] = sum_k att[h][k] * hEV[k][s]
#pragma unroll
  for (int q = 0; q < 2; q++) {
    int o = t + 256 * q;
    int h = o >> 7, s = o & 127;
    float a = 0.f;
    for (int k = 0; k < 30; k++) a += satt[h][k] * sEV[k][s];
    Pg[(size_t)row * 512 + o] = a;
  }
}

// ---------------- upd = P @ WV (per-head slices) + attsum*bV ----------------
__global__ __launch_bounds__(256) void k_upd(const float* __restrict__ Pg,
                                             const float* __restrict__ ats,
                                             const float* __restrict__ WV,
                                             const float* __restrict__ bV,
                                             float* __restrict__ U) {
  __shared__ float sWV[128][64];
  __shared__ float sP[8][512];
  const int t = threadIdx.x;
  const int row0 = blockIdx.x * 8;
#pragma unroll
  for (int q = 0; q < 32; q++) {
    int i = t + 256 * q;
    sWV[i >> 6][i & 63] = WV[i];
  }
#pragma unroll
  for (int q = 0; q < 16; q++) {
    int i = t + 256 * q;
    sP[i >> 9][i & 511] = Pg[(size_t)row0 * 512 + i];
  }
  __syncthreads();
  const int c = t & 63, rg = t >> 6;
  const int h = c >> 4;
  const int r0 = rg * 2;
  float a0 = 0.f, a1 = 0.f;
#pragma unroll
  for (int s0 = 0; s0 < 128; s0 += 4) {
    float w0 = sWV[s0][c], w1 = sWV[s0 + 1][c], w2 = sWV[s0 + 2][c], w3 = sWV[s0 + 3][c];
    const float4 p0 = *(const float4*)&sP[r0][h * 128 + s0];
    const float4 p1 = *(const float4*)&sP[r0 + 1][h * 128 + s0];
    a0 += p0.x * w0 + p0.y * w1 + p0.z * w2 + p0.w * w3;
    a1 += p1.x * w0 + p1.y * w1 + p1.z * w2 + p1.w * w3;
  }
  const float bv = bV[c];
  const int grow = row0 + r0;
  U[(size_t)grow * 64 + c] = a0 + ats[(size_t)grow * 4 + h] * bv;
  U[(size_t)(grow + 1) * 64 + c] = a1 + ats[(size_t)(grow + 1) * 4 + h] * bv;
}

// ---------------- hV = LN(hV + U @ WO + bO) ----------------
__global__ __launch_bounds__(256) void k_resln(const float* __restrict__ U,
                                               const float* __restrict__ WO,
                                               const float* __restrict__ bO,
                                               const float* __restrict__ g,
                                               const float* __restrict__ bb,
                                               float* __restrict__ hV) {
  __shared__ float sUt[64][16];
  __shared__ float sW[64][64];
  __shared__ float sO[16][64];
  const int t = threadIdx.x;
  const int row0 = blockIdx.x * 16;
#pragma unroll
  for (int q = 0; q < 4; q++) {
    int i = t + 256 * q;
    int r = i >> 6, cc = i & 63;
    sUt[cc][r] = U[(size_t)(row0 + r) * 64 + cc];
  }
#pragma unroll
  for (int q = 0; q < 16; q++) {
    int i = t + 256 * q;
    sW[i >> 6][i & 63] = WO[i];
  }
  __syncthreads();
  const int c = t & 63, rg = t >> 6;
  float acc[4] = {0.f, 0.f, 0.f, 0.f};
#pragma unroll
  for (int s = 0; s < 64; s++) {
    float w = sW[s][c];
    const float4 x = *(const float4*)&sUt[s][rg * 4];
    acc[0] += x.x * w; acc[1] += x.y * w; acc[2] += x.z * w; acc[3] += x.w * w;
  }
  const float bv = bO[c];
#pragma unroll
  for (int u = 0; u < 4; u++) sO[rg * 4 + u][c] = acc[u] + bv;
  __syncthreads();
  const int lane = t & 63, wv = t >> 6;
  const float gv = g[lane], bbv = bb[lane];
  for (int r = wv; r < 16; r += 4) {
    const int row = row0 + r;
    float x = hV[(size_t)row * 64 + lane] + sO[r][lane];
    float s1 = x, s2 = x * x;
#pragma unroll
    for (int off = 32; off; off >>= 1) {
      s1 += __shfl_xor(s1, off, 64);
      s2 += __shfl_xor(s2, off, 64);
    }
    float m = s1 * (1.f / 64.f);
    float var = s2 * (1.f / 64.f) - m * m;
    float inv = rsqrtf(var + 1e-5f);
    hV[(size_t)row * 64 + lane] = (x - m) * inv * gv + bbv;
  }
}

// ---------------- T = relu(hV @ W1 + bf1) ----------------
__global__ __launch_bounds__(256) void k_ffn1(const float* __restrict__ X,
                                              const float* __restrict__ W1,
                                              const float* __restrict__ bf1,
                                              float* __restrict__ T) {
  __shared__ float sXt[64][16];
  __shared__ float sW[32][256];
  const int t = threadIdx.x;
  const int row0 = blockIdx.x * 16;
#pragma unroll
  for (int q = 0; q < 4; q++) {
    int i = t + 256 * q;
    int r = i >> 6, cc = i & 63;
    sXt[cc][r] = X[(size_t)(row0 + r) * 64 + cc];
  }
  float acc[16];
#pragma unroll
  for (int u = 0; u < 16; u++) acc[u] = 0.f;
  for (int kc = 0; kc < 64; kc += 32) {
    __syncthreads();
#pragma unroll
    for (int q = 0; q < 32; q++) {
      int i = t + 256 * q;
      sW[i >> 8][i & 255] = W1[(size_t)(kc + (i >> 8)) * 256 + (i & 255)];
    }
    __syncthreads();
#pragma unroll
    for (int s = 0; s < 32; s++) {
      float w = sW[s][t];
      const float4 x0 = *(const float4*)&sXt[kc + s][0];
      const float4 x1 = *(const float4*)&sXt[kc + s][4];
      const float4 x2 = *(const float4*)&sXt[kc + s][8];
      const float4 x3 = *(const float4*)&sXt[kc + s][12];
      acc[0] += x0.x * w; acc[1] += x0.y * w; acc[2] += x0.z * w; acc[3] += x0.w * w;
      acc[4] += x1.x * w; acc[5] += x1.y * w; acc[6] += x1.z * w; acc[7] += x1.w * w;
      acc[8] += x2.x * w; acc[9] += x2.y * w; acc[10] += x2.z * w; acc[11] += x2.w * w;
      acc[12] += x3.x * w; acc[13] += x3.y * w; acc[14] += x3.z * w; acc[15] += x3.w * w;
    }
  }
  const float bv = bf1[t];
#pragma unroll
  for (int r = 0; r < 16; r++)
    T[(size_t)(row0 + r) * 256 + t] = fmaxf(acc[r] + bv, 0.f);
}

// ---------------- hV = LN(hV + T @ W2 + bf2) * mask ----------------
__global__ __launch_bounds__(256) void k_ffn2(const float* __restrict__ T,
                                              const float* __restrict__ W2,
                                              const float* __restrict__ bf2,
                                              const float* __restrict__ g,
                                              const float* __restrict__ bb,
                                              const float* __restrict__ mask,
                                              float* __restrict__ hV) {
  __shared__ float sTt[64][16];
  __shared__ float sW[64][64];
  __shared__ float sO[16][64];
  const int t = threadIdx.x;
  const int row0 = blockIdx.x * 16;
  const int c = t & 63, rg = t >> 6;
  float acc[4] = {0.f, 0.f, 0.f, 0.f};
  for (int kc = 0; kc < 256; kc += 64) {
    __syncthreads();
#pragma unroll
    for (int q = 0; q < 4; q++) {
      int i = t + 256 * q;
      int r = i >> 6, cc = i & 63;
      sTt[cc][r] = T[(size_t)(row0 + r) * 256 + kc + cc];
    }
#pragma unroll
    for (int q = 0; q < 16; q++) {
      int i = t + 256 * q;
      sW[i >> 6][i & 63] = W2[(size_t)(kc + (i >> 6)) * 64 + (i & 63)];
    }
    __syncthreads();
#pragma unroll
    for (int s = 0; s < 64; s++) {
      float w = sW[s][c];
      const float4 x = *(const float4*)&sTt[s][rg * 4];
      acc[0] += x.x * w; acc[1] += x.y * w; acc[2] += x.z * w; acc[3] += x.w * w;
    }
  }
  const float bv = bf2[c];
#pragma unroll
  for (int u = 0; u < 4; u++) sO[rg * 4 + u][c] = acc[u] + bv;
  __syncthreads();
  const int lane = t & 63, wv = t >> 6;
  const float gv = g[lane], bbv = bb[lane];
  for (int r = wv; r < 16; r += 4) {
    const int row = row0 + r;
    float x = hV[(size_t)row * 64 + lane] + sO[r][lane];
    float s1 = x, s2 = x * x;
#pragma unroll
    for (int off = 32; off; off >>= 1) {
      s1 += __shfl_xor(s1, off, 64);
      s2 += __shfl_xor(s2, off, 64);
    }
    float m = s1 * (1.f / 64.f);
    float var = s2 * (1.f / 64.f) - m * m;
    float inv = rsqrtf(var + 1e-5f);
    float y = (x - m) * inv * gv + bbv;
    hV[(size_t)row * 64 + lane] = y * mask[row];
  }
}

// ---------------- out = hV @ W_out + b_out ----------------
__global__ __launch_bounds__(256) void k_out(const float* __restrict__ hV,
                                             const float* __restrict__ Wo,
                                             const float* __restrict__ bo,
                                             float* __restrict__ out) {
  const int t = threadIdx.x;
  const int lane = t & 63, wv = t >> 6;
  const int row = blockIdx.x * 4 + wv;
  float v = hV[(size_t)row * 64 + lane] * Wo[lane];
#pragma unroll
  for (int off = 32; off; off >>= 1) v += __shfl_xor(v, off, 64);
  if (lane == 0) out[row] = v + bo[0];
}

extern "C" void kernel_launch(void* const* d_in, const int* in_sizes, int n_in,
                              void* d_out, int out_size, void* d_ws, size_t ws_size,
                              hipStream_t stream) {
  const float* coords = (const float*)d_in[0];
  const float* nodef = (const float*)d_in[1];
  const float* mask = (const float*)d_in[2];
  const float* W_node = (const float*)d_in[3];
  const float* b_node = (const float*)d_in[4];
  const float* W_ee = (const float*)d_in[5];
  const float* g_eln = (const float*)d_in[6];
  const float* b_eln = (const float*)d_in[7];
  const float* W_ep = (const float*)d_in[8];
  const float* b_ep = (const float*)d_in[9];
  const float* WQ = (const float*)d_in[10];
  const float* bQ = (const float*)d_in[11];
  const float* WK = (const float*)d_in[12];
  const float* bK = (const float*)d_in[13];
  const float* WV = (const float*)d_in[14];
  const float* bV = (const float*)d_in[15];
  const float* WO = (const float*)d_in[16];
  const float* bO = (const float*)d_in[17];
  const float* g1 = (const float*)d_in[18];
  const float* b1 = (const float*)d_in[19];
  const float* W1 = (const float*)d_in[20];
  const float* bf1 = (const float*)d_in[21];
  const float* W2 = (const float*)d_in[22];
  const float* bf2 = (const float*)d_in[23];
  const float* g2 = (const float*)d_in[24];
  const float* b2 = (const float*)d_in[25];
  const float* W_out = (const float*)d_in[26];
  const float* b_out = (const float*)d_in[27];

  float* ws = (float*)d_ws;
  float* hV = ws;                      // 1,048,576 f
  float* Qb = hV + 1048576;            // 1,048,576 f  (Q, later upd)
  float* QW = Qb + 1048576;            // 8,388,608 f
  float* Pg = QW + 8388608;            // 8,388,608 f
  float* qbK = Pg + 8388608;           // 65,536 f
  float* ats = qbK + 65536;            // 65,536 f
  float* Tb = ats + 65536;             // 4,194,304 f
  float* Dnb = Tb + 4194304;           // 491,520 f
  int* Eidx = (int*)(Dnb + 491520);    // 491,520 i  (total ~96.7 MB)

  k_node<<<256, 256, 0, stream>>>(nodef, W_node, b_node, hV);
  k_edges<<<16384, 256, 0, stream>>>(coords, mask, Eidx, Dnb);
  for (int l = 0; l < 4; l++) {
    k_gemm64<<<256, 256, 0, stream>>>(hV, WQ + l * 4096, bQ + l * 64, Qb);
    k_qw<<<256, 256, 0, stream>>>(Qb, WK + l * 8192, bK + l * 64, QW, qbK);
    k_attn<<<16384, 256, 0, stream>>>(Dnb, Eidx, hV, mask, QW, qbK,
                                      W_ee, g_eln, b_eln, W_ep, b_ep, Pg, ats);
    k_upd<<<2048, 256, 0, stream>>>(Pg, ats, WV + l * 8192, bV + l * 64, Qb);
    k_resln<<<1024, 256, 0, stream>>>(Qb, WO + l * 4096, bO + l * 64,
                                      g1 + l * 64, b1 + l * 64, hV);
    k_ffn1<<<1024, 256, 0, stream>>>(hV, W1 + l * 16384, bf1 + l * 256, Tb);
    k_ffn2<<<1024, 256, 0, stream>>>(Tb, W2 + l * 16384, bf2 + l * 64,
                                     g2 + l * 64, b2 + l * 64, mask, hV);
  }
  k_out<<<4096, 256, 0, stream>>>(hV, W_out, b_out, (float*)d_out);
}

// Round 2
// 1499.648 us; speedup vs baseline: 1.1220x; 1.1220x over previous
//
#include <hip/hip_runtime.h>
#include <hip/hip_fp16.h>

#define L_ 2048
#define NROW 16384
#define FIN 1038

// ---------------- node embedding: hV = node_features @ W_node + b ----------------
__global__ __launch_bounds__(256) void k_node(const float* __restrict__ X,
                                              const float* __restrict__ W,
                                              const float* __restrict__ bias,
                                              float* __restrict__ out) {
  __shared__ float As[64][16];
  __shared__ float Ws[16][64];
  const int t = threadIdx.x;
  const int row0 = blockIdx.x * 64;
  const int c = t & 63, rg = t >> 6;
  float acc[16];
#pragma unroll
  for (int u = 0; u < 16; u++) acc[u] = 0.f;
  for (int kc = 0; kc < FIN; kc += 16) {
    const int kk = (FIN - kc < 16) ? (FIN - kc) : 16;
    __syncthreads();
#pragma unroll
    for (int q = 0; q < 4; q++) {
      int i = t + 256 * q;
      int r = i >> 4, cc = i & 15;
      As[r][cc] = (cc < kk) ? X[(size_t)(row0 + r) * FIN + kc + cc] : 0.f;
      int s = i >> 6, c2 = i & 63;
      Ws[s][c2] = (s < kk) ? W[(size_t)(kc + s) * 64 + c2] : 0.f;
    }
    __syncthreads();
#pragma unroll
    for (int s0 = 0; s0 < 16; s0 += 4) {
      float w0 = Ws[s0][c], w1 = Ws[s0 + 1][c], w2 = Ws[s0 + 2][c], w3 = Ws[s0 + 3][c];
#pragma unroll
      for (int u = 0; u < 16; u++) {
        const float4 a = *(const float4*)&As[rg + 4 * u][s0];
        acc[u] += a.x * w0 + a.y * w1 + a.z * w2 + a.w * w3;
      }
    }
  }
  const float bb = bias[c];
#pragma unroll
  for (int u = 0; u < 16; u++)
    out[(size_t)(row0 + rg + 4 * u) * 64 + c] = acc[u] + bb;
}

// ---------------- edges: distances + histogram-select top-30 + E_ln precompute ----------------
__global__ __launch_bounds__(256) void k_edges(const float* __restrict__ coords,
                                               const float* __restrict__ mask,
                                               const float* __restrict__ Wee,
                                               const float* __restrict__ geln,
                                               const float* __restrict__ beln,
                                               int* __restrict__ Eidx,
                                               __half* __restrict__ Eln) {
  const int row = blockIdx.x;
  const int b = row >> 11;
  const int t = threadIdx.x;
  const int lane = t & 63, wid = t >> 6;
  __shared__ float sredf[4];
  __shared__ unsigned int hist[2048];
  __shared__ unsigned int wtot[4];
  __shared__ int s_bin, s_need;
  __shared__ int s_lcnt, s_outcnt;
  __shared__ unsigned int s_lkey[64];
  __shared__ int s_lidx[64];
  __shared__ int s_sel[64];
  __shared__ float sD[30];
  __shared__ int sJ[30];
  __shared__ float sWee[16][16];
  __shared__ float sg[16], sb[16];
  __shared__ float sRBF[30][16];

  if (t < 256) sWee[t >> 4][t & 15] = Wee[t];
  if (t < 16) { sg[t] = geln[t]; sb[t] = beln[t]; }
  if (t == 0) { s_lcnt = 0; s_outcnt = 0; }

  const float* cb = coords + (size_t)b * (L_ * 3);
  const int i = row & (L_ - 1);
  const float cix = cb[i * 3 + 0], ciy = cb[i * 3 + 1], ciz = cb[i * 3 + 2];
  const float mi = mask[row];
  const float* mb = mask + (size_t)b * L_;
  float d[8], mj[8];
  float dmax = 0.f;
#pragma unroll
  for (int u = 0; u < 8; u++) {
    int j = t + 256 * u;
    float dx = cix - cb[j * 3 + 0];
    float dy = ciy - cb[j * 3 + 1];
    float dz = ciz - cb[j * 3 + 2];
    float dist = sqrtf(dx * dx + dy * dy + dz * dz + 1e-6f);
    d[u] = dist;
    mj[u] = mb[j];
    dmax = fmaxf(dmax, dist);
  }
#pragma unroll
  for (int off = 32; off; off >>= 1) dmax = fmaxf(dmax, __shfl_xor(dmax, off, 64));
  if (lane == 0) sredf[wid] = dmax;
#pragma unroll
  for (int q = 0; q < 8; q++) hist[t * 8 + q] = 0u;
  __syncthreads();
  dmax = fmaxf(fmaxf(sredf[0], sredf[1]), fmaxf(sredf[2], sredf[3]));
  const float scale = 1024.0f / fmaxf(dmax, 1e-20f);
  float adj[8];
  int bin[8];
#pragma unroll
  for (int u = 0; u < 8; u++) {
    adj[u] = d[u] + (1.f - mi * mj[u]) * dmax;
    int bi = (int)(adj[u] * scale);
    bin[u] = bi < 2047 ? bi : 2047;
    atomicAdd(&hist[bin[u]], 1u);
  }
  __syncthreads();
  // hierarchical scan over 2048 bins; locate rank-30 boundary bin
  unsigned int c[8];
  unsigned int local = 0;
#pragma unroll
  for (int q = 0; q < 8; q++) { c[q] = hist[t * 8 + q]; local += c[q]; }
  unsigned int incl = local;
#pragma unroll
  for (int off = 1; off < 64; off <<= 1) {
    unsigned int v = __shfl_up(incl, off, 64);
    if (lane >= off) incl += v;
  }
  if (lane == 63) wtot[wid] = incl;
  __syncthreads();
  unsigned int excl = incl - local;
  for (int w = 0; w < wid; w++) excl += wtot[w];
  if (excl < 30u && excl + local >= 30u) {
    unsigned int run = excl;
#pragma unroll
    for (int q = 0; q < 8; q++) {
      if (run + c[q] >= 30u) { s_bin = t * 8 + q; s_need = 30 - (int)run; break; }
      run += c[q];
    }
  }
  __syncthreads();
  const int tbin = s_bin;
  int pos[8];
#pragma unroll
  for (int u = 0; u < 8; u++) {
    pos[u] = -1;
    if (bin[u] == tbin) {
      int p = atomicAdd(&s_lcnt, 1);
      if (p < 64) { s_lkey[p] = __float_as_uint(adj[u]); s_lidx[p] = t + 256 * u; pos[u] = p; }
    }
  }
  __syncthreads();
  {
    int n = s_lcnt < 64 ? s_lcnt : 64;
    if (t < n) {
      unsigned int k0 = s_lkey[t];
      int j0 = s_lidx[t];
      int r = 0;
      for (int m = 0; m < n; m++) {
        unsigned int km = s_lkey[m];
        r += (km < k0) || (km == k0 && s_lidx[m] < j0);
      }
      s_sel[t] = (r < s_need) ? 1 : 0;
    }
  }
  __syncthreads();
#pragma unroll
  for (int u = 0; u < 8; u++) {
    bool sel = (bin[u] < tbin) || (pos[u] >= 0 && s_sel[pos[u]]);
    if (sel) {
      int o = atomicAdd(&s_outcnt, 1);
      if (o < 30) { sJ[o] = t + 256 * u; sD[o] = adj[u]; }
    }
  }
  __syncthreads();
  if (t < 30) Eidx[(size_t)row * 30 + t] = sJ[t];
  for (int o = t; o < 480; o += 256) {
    int k = o >> 4, s = o & 15;
    float mu = 2.0f + (4.0f / 3.0f) * (float)s;
    float z = (sD[k] - mu) * 0.8f;
    sRBF[k][s] = __expf(-z * z);
  }
  __syncthreads();
  if (t < 240) {
    int k = t >> 3, p = t & 7;
    int c0 = p * 2, c1 = c0 + 1;
    float e0 = 0.f, e1 = 0.f;
#pragma unroll
    for (int s = 0; s < 16; s++) {
      float r = sRBF[k][s];
      e0 += r * sWee[s][c0];
      e1 += r * sWee[s][c1];
    }
    float s1 = e0 + e1, s2 = e0 * e0 + e1 * e1;
#pragma unroll
    for (int m = 1; m < 8; m <<= 1) {
      s1 += __shfl_xor(s1, m, 64);
      s2 += __shfl_xor(s2, m, 64);
    }
    float mean = s1 * (1.f / 16.f);
    float var = s2 * (1.f / 16.f) - mean * mean;
    float inv = rsqrtf(var + 1e-5f);
    Eln[(size_t)row * 480 + k * 16 + c0] = __float2half((e0 - mean) * inv * sg[c0] + sb[c0]);
    Eln[(size_t)row * 480 + k * 16 + c1] = __float2half((e1 - mean) * inv * sg[c1] + sb[c1]);
  }
}

// ---------------- generic 64x64 GEMM + bias (Q projection) ----------------
__global__ __launch_bounds__(256) void k_gemm64(const float* __restrict__ X,
                                                const float* __restrict__ W,
                                                const float* __restrict__ bias,
                                                float* __restrict__ out) {
  __shared__ float Xs[64][64];
  __shared__ float Ws[64][64];
  const int t = threadIdx.x;
  const int row0 = blockIdx.x * 64;
#pragma unroll
  for (int q = 0; q < 16; q++) {
    int i = t + 256 * q;
    int r = i >> 6, c = i & 63;
    Xs[r][c] = X[(size_t)(row0 + r) * 64 + c];
    Ws[r][c] = W[i];
  }
  __syncthreads();
  const int c = t & 63, rg = t >> 6;
  float acc[16];
#pragma unroll
  for (int u = 0; u < 16; u++) acc[u] = 0.f;
#pragma unroll
  for (int s0 = 0; s0 < 64; s0 += 4) {
    float w0 = Ws[s0][c], w1 = Ws[s0 + 1][c], w2 = Ws[s0 + 2][c], w3 = Ws[s0 + 3][c];
#pragma unroll
    for (int u = 0; u < 16; u++) {
      const float4 a = *(const float4*)&Xs[rg + 4 * u][s0];
      acc[u] += a.x * w0 + a.y * w1 + a.z * w2 + a.w * w3;
    }
  }
  const float bb = bias[c];
#pragma unroll
  for (int u = 0; u < 16; u++)
    out[(size_t)(row0 + rg + 4 * u) * 64 + c] = acc[u] + bb;
}

// ---------------- qw[row][s][h] = sum_d Q[row][h*16+d] * WK[s][h*16+d]; qbK = Q.bK ----------------
__global__ __launch_bounds__(256) void k_qw(const float* __restrict__ Q,
                                            const float* __restrict__ WK,
                                            const float* __restrict__ bK,
                                            float* __restrict__ QW,
                                            float* __restrict__ qbK) {
  __shared__ float sQ[64][64];
  __shared__ float sWK[128][64];
  const int t = threadIdx.x;
  const int row0 = blockIdx.x * 64;
#pragma unroll
  for (int q = 0; q < 16; q++) {
    int i = t + 256 * q;
    sQ[i >> 6][i & 63] = Q[(size_t)(row0 + (i >> 6)) * 64 + (i & 63)];
  }
#pragma unroll
  for (int q = 0; q < 32; q++) {
    int i = t + 256 * q;
    sWK[i >> 6][i & 63] = WK[i];
  }
  __syncthreads();
  {
    int r = t >> 2, hh = t & 3;
    float a = 0.f;
#pragma unroll
    for (int d = 0; d < 16; d++) a += sQ[r][hh * 16 + d] * bK[hh * 16 + d];
    qbK[(size_t)(row0 + r) * 4 + hh] = a;
  }
  const int h = t & 3, s2 = t >> 2;
  for (int r = 0; r < 64; r++) {
    float a0 = 0.f, a1 = 0.f;
#pragma unroll
    for (int d0 = 0; d0 < 16; d0 += 4) {
      const float4 q4 = *(const float4*)&sQ[r][h * 16 + d0];
      const float4 wa = *(const float4*)&sWK[s2][h * 16 + d0];
      const float4 wb = *(const float4*)&sWK[s2 + 64][h * 16 + d0];
      a0 += q4.x * wa.x + q4.y * wa.y + q4.z * wa.z + q4.w * wa.w;
      a1 += q4.x * wb.x + q4.y * wb.y + q4.z * wb.z + q4.w * wb.w;
    }
    QW[(size_t)(row0 + r) * 512 + s2 * 4 + h] = a0;
    QW[(size_t)(row0 + r) * 512 + (s2 + 64) * 4 + h] = a1;
  }
}

// ---------------- per-row attention core: hEV, logits, softmax, P ----------------
__global__ __launch_bounds__(256) void k_attn(
    const __half* __restrict__ Eln, const int* __restrict__ Eidx,
    const float* __restrict__ hV, const float* __restrict__ mask,
    const float* __restrict__ QWg, const float* __restrict__ qbKg,
    const float* __restrict__ Wep, const float* __restrict__ bep,
    float* __restrict__ Pg, float* __restrict__ attsum) {
  const int row = blockIdx.x;
  const int b = row >> 11;
  const int t = threadIdx.x;
  const int lane = t & 63, wid = t >> 6;
  __shared__ float sEV[30][132];
  __shared__ float sQW[4][128];
  __shared__ float sE[30][17];
  __shared__ float sWep[16][64];
  __shared__ float sbep[64];
  __shared__ float sqb[4];
  __shared__ float slog[4][32];
  __shared__ float satt[4][32];
  __shared__ float smk[32];
  __shared__ int sIdx[30];

  if (t < 64) sbep[t] = bep[t];
  for (int q = t; q < 1024; q += 256) sWep[q >> 6][q & 63] = Wep[q];
  if (t < 4) sqb[t] = qbKg[(size_t)row * 4 + t];
  if (t < 30) {
    int j = Eidx[(size_t)row * 30 + t];
    sIdx[t] = j;
    smk[t] = mask[(b << 11) + j] * mask[row];
  }
  for (int o = t; o < 480; o += 256)
    sE[o >> 4][o & 15] = __half2float(Eln[(size_t)row * 480 + o]);
#pragma unroll
  for (int q = 0; q < 2; q++) {
    int o = t + 256 * q;
    float v = QWg[(size_t)row * 512 + o];
    sQW[o & 3][o >> 2] = v;
  }
  __syncthreads();
  // hEV: edge half (E @ Wep + bep) and gathered hV half
#pragma unroll
  for (int q = 0; q < 8; q++) {
    int o = t + 256 * q;
    if (o < 1920) {
      int k = o >> 6, c = o & 63;
      float a = sbep[c];
#pragma unroll
      for (int s = 0; s < 16; s++) a += sE[k][s] * sWep[s][c];
      sEV[k][c] = a;
      sEV[k][64 + c] = hV[((size_t)(b << 11) + sIdx[k]) * 64 + c];
    }
  }
  __syncthreads();
  // logits: 2 threads per (k,h), 64-channel halves
  if (t < 240) {
    int k = t >> 3, h = (t >> 1) & 3, z = t & 1;
    float a = 0.f;
    const int s00 = z * 64;
#pragma unroll
    for (int s0 = 0; s0 < 64; s0 += 4) {
      const float4 e = *(const float4*)&sEV[k][s00 + s0];
      const float4 w = *(const float4*)&sQW[h][s00 + s0];
      a += e.x * w.x + e.y * w.y + e.z * w.z + e.w * w.w;
    }
    a += __shfl_xor(a, 1, 64);
    if (z == 0) {
      float lg = (a + sqb[h]) * 0.25f;
      if (!(smk[k] > 0.f)) lg = -3.402823466e38f;
      slog[h][k] = lg;
    }
  }
  __syncthreads();
  // softmax: wave w handles head w
  {
    float lg = (lane < 30) ? slog[wid][lane] : -3.402823466e38f;
    float mx = lg;
#pragma unroll
    for (int off = 32; off; off >>= 1) mx = fmaxf(mx, __shfl_xor(mx, off, 64));
    float e = (lane < 30) ? __expf(lg - mx) : 0.f;
    float den = e;
#pragma unroll
    for (int off = 32; off; off >>= 1) den += __shfl_xor(den, off, 64);
    float inv = 1.f / den;
    float av = (lane < 30) ? e * inv * smk[lane] : 0.f;
    if (lane < 30) satt[wid][lane] = av;
    float ss = av;
#pragma unroll
    for (int off = 32; off; off >>= 1) ss += __shfl_xor(ss, off, 64);
    if (lane == 0) attsum[(size_t)row * 4 + wid] = ss;
  }
  __syncthreads();
  // P[row][h*128+s] = sum_k att[h][k] * hEV[k][s]
#pragma unroll
  for (int q = 0; q < 2; q++) {
    int o = t + 256 * q;
    int h = o >> 7, s = o & 127;
    float a = 0.f;
    for (int k = 0; k < 30; k++) a += satt[h][k] * sEV[k][s];
    Pg[(size_t)row * 512 + o] = a;
  }
}

// ---------------- upd = P @ WV (per-head slices) + attsum*bV ----------------
__global__ __launch_bounds__(256) void k_upd(const float* __restrict__ Pg,
                                             const float* __restrict__ ats,
                                             const float* __restrict__ WV,
                                             const float* __restrict__ bV,
                                             float* __restrict__ U) {
  __shared__ float sWV[128][64];
  __shared__ float sP[8][512];
  const int t = threadIdx.x;
  const int row0 = blockIdx.x * 8;
#pragma unroll
  for (int q = 0; q < 32; q++) {
    int i = t + 256 * q;
    sWV[i >> 6][i & 63] = WV[i];
  }
#pragma unroll
  for (int q = 0; q < 16; q++) {
    int i = t + 256 * q;
    sP[i >> 9][i & 511] = Pg[(size_t)row0 * 512 + i];
  }
  __syncthreads();
  const int c = t & 63, rg = t >> 6;
  const int h = c >> 4;
  const int r0 = rg * 2;
  float a0 = 0.f, a1 = 0.f;
#pragma unroll
  for (int s0 = 0; s0 < 128; s0 += 4) {
    float w0 = sWV[s0][c], w1 = sWV[s0 + 1][c], w2 = sWV[s0 + 2][c], w3 = sWV[s0 + 3][c];
    const float4 p0 = *(const float4*)&sP[r0][h * 128 + s0];
    const float4 p1 = *(const float4*)&sP[r0 + 1][h * 128 + s0];
    a0 += p0.x * w0 + p0.y * w1 + p0.z * w2 + p0.w * w3;
    a1 += p1.x * w0 + p1.y * w1 + p1.z * w2 + p1.w * w3;
  }
  const float bv = bV[c];
  const int grow = row0 + r0;
  U[(size_t)grow * 64 + c] = a0 + ats[(size_t)grow * 4 + h] * bv;
  U[(size_t)(grow + 1) * 64 + c] = a1 + ats[(size_t)(grow + 1) * 4 + h] * bv;
}

// ---------------- hV = LN(hV + U @ WO + bO) ----------------
__global__ __launch_bounds__(256) void k_resln(const float* __restrict__ U,
                                               const float* __restrict__ WO,
                                               const float* __restrict__ bO,
                                               const float* __restrict__ g,
                                               const float* __restrict__ bb,
                                               float* __restrict__ hV) {
  __shared__ float sUt[64][16];
  __shared__ float sW[64][64];
  __shared__ float sO[16][64];
  const int t = threadIdx.x;
  const int row0 = blockIdx.x * 16;
#pragma unroll
  for (int q = 0; q < 4; q++) {
    int i = t + 256 * q;
    int r = i >> 6, cc = i & 63;
    sUt[cc][r] = U[(size_t)(row0 + r) * 64 + cc];
  }
#pragma unroll
  for (int q = 0; q < 16; q++) {
    int i = t + 256 * q;
    sW[i >> 6][i & 63] = WO[i];
  }
  __syncthreads();
  const int c = t & 63, rg = t >> 6;
  float acc[4] = {0.f, 0.f, 0.f, 0.f};
#pragma unroll
  for (int s = 0; s < 64; s++) {
    float w = sW[s][c];
    const float4 x = *(const float4*)&sUt[s][rg * 4];
    acc[0] += x.x * w; acc[1] += x.y * w; acc[2] += x.z * w; acc[3] += x.w * w;
  }
  const float bv = bO[c];
#pragma unroll
  for (int u = 0; u < 4; u++) sO[rg * 4 + u][c] = acc[u] + bv;
  __syncthreads();
  const int lane = t & 63, wv = t >> 6;
  const float gv = g[lane], bbv = bb[lane];
  for (int r = wv; r < 16; r += 4) {
    const int row = row0 + r;
    float x = hV[(size_t)row * 64 + lane] + sO[r][lane];
    float s1 = x, s2 = x * x;
#pragma unroll
    for (int off = 32; off; off >>= 1) {
      s1 += __shfl_xor(s1, off, 64);
      s2 += __shfl_xor(s2, off, 64);
    }
    float m = s1 * (1.f / 64.f);
    float var = s2 * (1.f / 64.f) - m * m;
    float inv = rsqrtf(var + 1e-5f);
    hV[(size_t)row * 64 + lane] = (x - m) * inv * gv + bbv;
  }
}

// ---------------- T = relu(hV @ W1 + bf1) ----------------
__global__ __launch_bounds__(256) void k_ffn1(const float* __restrict__ X,
                                              const float* __restrict__ W1,
                                              const float* __restrict__ bf1,
                                              float* __restrict__ T) {
  __shared__ float sXt[64][16];
  __shared__ float sW[32][256];
  const int t = threadIdx.x;
  const int row0 = blockIdx.x * 16;
#pragma unroll
  for (int q = 0; q < 4; q++) {
    int i = t + 256 * q;
    int r = i >> 6, cc = i & 63;
    sXt[cc][r] = X[(size_t)(row0 + r) * 64 + cc];
  }
  float acc[16];
#pragma unroll
  for (int u = 0; u < 16; u++) acc[u] = 0.f;
  for (int kc = 0; kc < 64; kc += 32) {
    __syncthreads();
#pragma unroll
    for (int q = 0; q < 32; q++) {
      int i = t + 256 * q;
      sW[i >> 8][i & 255] = W1[(size_t)(kc + (i >> 8)) * 256 + (i & 255)];
    }
    __syncthreads();
#pragma unroll
    for (int s = 0; s < 32; s++) {
      float w = sW[s][t];
      const float4 x0 = *(const float4*)&sXt[kc + s][0];
      const float4 x1 = *(const float4*)&sXt[kc + s][4];
      const float4 x2 = *(const float4*)&sXt[kc + s][8];
      const float4 x3 = *(const float4*)&sXt[kc + s][12];
      acc[0] += x0.x * w; acc[1] += x0.y * w; acc[2] += x0.z * w; acc[3] += x0.w * w;
      acc[4] += x1.x * w; acc[5] += x1.y * w; acc[6] += x1.z * w; acc[7] += x1.w * w;
      acc[8] += x2.x * w; acc[9] += x2.y * w; acc[10] += x2.z * w; acc[11] += x2.w * w;
      acc[12] += x3.x * w; acc[13] += x3.y * w; acc[14] += x3.z * w; acc[15] += x3.w * w;
    }
  }
  const float bv = bf1[t];
#pragma unroll
  for (int r = 0; r < 16; r++)
    T[(size_t)(row0 + r) * 256 + t] = fmaxf(acc[r] + bv, 0.f);
}

// ---------------- hV = LN(hV + T @ W2 + bf2) * mask ----------------
__global__ __launch_bounds__(256) void k_ffn2(const float* __restrict__ T,
                                              const float* __restrict__ W2,
                                              const float* __restrict__ bf2,
                                              const float* __restrict__ g,
                                              const float* __restrict__ bb,
                                              const float* __restrict__ mask,
                                              float* __restrict__ hV) {
  __shared__ float sTt[64][16];
  __shared__ float sW[64][64];
  __shared__ float sO[16][64];
  const int t = threadIdx.x;
  const int row0 = blockIdx.x * 16;
  const int c = t & 63, rg = t >> 6;
  float acc[4] = {0.f, 0.f, 0.f, 0.f};
  for (int kc = 0; kc < 256; kc += 64) {
    __syncthreads();
#pragma unroll
    for (int q = 0; q < 4; q++) {
      int i = t + 256 * q;
      int r = i >> 6, cc = i & 63;
      sTt[cc][r] = T[(size_t)(row0 + r) * 256 + kc + cc];
    }
#pragma unroll
    for (int q = 0; q < 16; q++) {
      int i = t + 256 * q;
      sW[i >> 6][i & 63] = W2[(size_t)(kc + (i >> 6)) * 64 + (i & 63)];
    }
    __syncthreads();
#pragma unroll
    for (int s = 0; s < 64; s++) {
      float w = sW[s][c];
      const float4 x = *(const float4*)&sTt[s][rg * 4];
      acc[0] += x.x * w; acc[1] += x.y * w; acc[2] += x.z * w; acc[3] += x.w * w;
    }
  }
  const float bv = bf2[c];
#pragma unroll
  for (int u = 0; u < 4; u++) sO[rg * 4 + u][c] = acc[u] + bv;
  __syncthreads();
  const int lane = t & 63, wv = t >> 6;
  const float gv = g[lane], bbv = bb[lane];
  for (int r = wv; r < 16; r += 4) {
    const int row = row0 + r;
    float x = hV[(size_t)row * 64 + lane] + sO[r][lane];
    float s1 = x, s2 = x * x;
#pragma unroll
    for (int off = 32; off; off >>= 1) {
      s1 += __shfl_xor(s1, off, 64);
      s2 += __shfl_xor(s2, off, 64);
    }
    float m = s1 * (1.f / 64.f);
    float var = s2 * (1.f / 64.f) - m * m;
    float inv = rsqrtf(var + 1e-5f);
    float y = (x - m) * inv * gv + bbv;
    hV[(size_t)row * 64 + lane] = y * mask[row];
  }
}

// ---------------- out = hV @ W_out + b_out ----------------
__global__ __launch_bounds__(256) void k_out(const float* __restrict__ hV,
                                             const float* __restrict__ Wo,
                                             const float* __restrict__ bo,
                                             float* __restrict__ out) {
  const int t = threadIdx.x;
  const int lane = t & 63, wv = t >> 6;
  const int row = blockIdx.x * 4 + wv;
  float v = hV[(size_t)row * 64 + lane] * Wo[lane];
#pragma unroll
  for (int off = 32; off; off >>= 1) v += __shfl_xor(v, off, 64);
  if (lane == 0) out[row] = v + bo[0];
}

extern "C" void kernel_launch(void* const* d_in, const int* in_sizes, int n_in,
                              void* d_out, int out_size, void* d_ws, size_t ws_size,
                              hipStream_t stream) {
  const float* coords = (const float*)d_in[0];
  const float* nodef = (const float*)d_in[1];
  const float* mask = (const float*)d_in[2];
  const float* W_node = (const float*)d_in[3];
  const float* b_node = (const float*)d_in[4];
  const float* W_ee = (const float*)d_in[5];
  const float* g_eln = (const float*)d_in[6];
  const float* b_eln = (const float*)d_in[7];
  const float* W_ep = (const float*)d_in[8];
  const float* b_ep = (const float*)d_in[9];
  const float* WQ = (const float*)d_in[10];
  const float* bQ = (const float*)d_in[11];
  const float* WK = (const float*)d_in[12];
  const float* bK = (const float*)d_in[13];
  const float* WV = (const float*)d_in[14];
  const float* bV = (const float*)d_in[15];
  const float* WO = (const float*)d_in[16];
  const float* bO = (const float*)d_in[17];
  const float* g1 = (const float*)d_in[18];
  const float* b1 = (const float*)d_in[19];
  const float* W1 = (const float*)d_in[20];
  const float* bf1 = (const float*)d_in[21];
  const float* W2 = (const float*)d_in[22];
  const float* bf2 = (const float*)d_in[23];
  const float* g2 = (const float*)d_in[24];
  const float* b2 = (const float*)d_in[25];
  const float* W_out = (const float*)d_in[26];
  const float* b_out = (const float*)d_in[27];

  float* ws = (float*)d_ws;
  float* hV = ws;                          // 1,048,576 f
  float* Qb = hV + 1048576;                // 1,048,576 f  (Q, later upd)
  float* QW = Qb + 1048576;                // 8,388,608 f  (also aliased as Tb)
  float* Pg = QW + 8388608;                // 8,388,608 f
  float* qbK = Pg + 8388608;               // 65,536 f
  float* ats = qbK + 65536;                // 65,536 f
  int* Eidx = (int*)(ats + 65536);         // 491,520 i
  __half* Eln = (__half*)(Eidx + 491520);  // 7,864,320 h   (total ~93.7 MB)
  float* Tb = QW;                          // alias: lifetime disjoint from QW

  k_node<<<256, 256, 0, stream>>>(nodef, W_node, b_node, hV);
  k_edges<<<16384, 256, 0, stream>>>(coords, mask, W_ee, g_eln, b_eln, Eidx, Eln);
  for (int l = 0; l < 4; l++) {
    k_gemm64<<<256, 256, 0, stream>>>(hV, WQ + l * 4096, bQ + l * 64, Qb);
    k_qw<<<256, 256, 0, stream>>>(Qb, WK + l * 8192, bK + l * 64, QW, qbK);
    k_attn<<<16384, 256, 0, stream>>>(Eln, Eidx, hV, mask, QW, qbK,
                                      W_ep, b_ep, Pg, ats);
    k_upd<<<2048, 256, 0, stream>>>(Pg, ats, WV + l * 8192, bV + l * 64, Qb);
    k_resln<<<1024, 256, 0, stream>>>(Qb, WO + l * 4096, bO + l * 64,
                                      g1 + l * 64, b1 + l * 64, hV);
    k_ffn1<<<1024, 256, 0, stream>>>(hV, W1 + l * 16384, bf1 + l * 256, Tb);
    k_ffn2<<<1024, 256, 0, stream>>>(Tb, W2 + l * 16384, bf2 + l * 64,
                                     g2 + l * 64, b2 + l * 64, mask, hV);
  }
  k_out<<<4096, 256, 0, stream>>>(hV, W_out, b_out, (float*)d_out);
}

// Round 3
// 1477.870 us; speedup vs baseline: 1.1385x; 1.0147x over previous
//
#include <hip/hip_runtime.h>
#include <hip/hip_fp16.h>

#define L_ 2048
#define NROW 16384
#define FIN 1038

// ---------------- node embedding part: Part[split] = X[:, ks:ke] @ W[ks:ke, :] ----------------
// Barrier-free: each wave owns 32 rows x 64 cols with wave-private LDS staging.
// Thread micro-tile 4 rows x 8 cols; K-chunk 32 with register prefetch.
__global__ __launch_bounds__(256, 2) void k_node_part(const float* __restrict__ X,
                                                      const float* __restrict__ W,
                                                      float* __restrict__ Part) {
  const int rb = blockIdx.x >> 2;
  const int split = blockIdx.x & 3;
  const int kStart = split * 260;
  const int kEnd = (split == 3) ? FIN : (kStart + 260);
  const int t = threadIdx.x;
  const int wid = t >> 6, lane = t & 63;
  const int r0 = rb * 128 + wid * 32;
  __shared__ float lds[4][32 * 36 + 32 * 64];
  float* Xs = lds[wid];
  float* Ws = lds[wid] + 32 * 36;
  const int rr = lane >> 3;        // 0..7  (row group / staging row sub)
  const int mm = lane & 7;         // 0..7  (col group / staging col sub)
  const int jj = lane >> 4;        // 0..3  (W staging row sub)
  const int cc = (lane & 15) * 4;  // 0..60 (W staging col)

  float acc[4][8];
#pragma unroll
  for (int u = 0; u < 4; u++)
#pragma unroll
    for (int v = 0; v < 8; v++) acc[u][v] = 0.f;

  float4 px[4], pw[8];
  // preload first chunk
  {
    const int kc = kStart;
#pragma unroll
    for (int q = 0; q < 4; q++) {
      const int row = r0 + 8 * q + rr;
      const int col = kc + 4 * mm;
      float4 v = make_float4(0.f, 0.f, 0.f, 0.f);
      if (col + 4 <= kEnd) v = *(const float4*)&X[(size_t)row * FIN + col];
      else {
        const float* xr = &X[(size_t)row * FIN];
        if (col + 0 < kEnd) v.x = xr[col + 0];
        if (col + 1 < kEnd) v.y = xr[col + 1];
        if (col + 2 < kEnd) v.z = xr[col + 2];
        if (col + 3 < kEnd) v.w = xr[col + 3];
      }
      px[q] = v;
    }
#pragma unroll
    for (int q = 0; q < 8; q++) {
      const int j = kc + 4 * q + jj;
      pw[q] = (j < kEnd) ? *(const float4*)&W[(size_t)j * 64 + cc]
                         : make_float4(0.f, 0.f, 0.f, 0.f);
    }
  }

  for (int kc = kStart; kc < kEnd; kc += 32) {
    // stage current chunk (wave-private -> no barrier)
#pragma unroll
    for (int q = 0; q < 4; q++)
      *(float4*)&Xs[(8 * q + rr) * 36 + 4 * mm] = px[q];
#pragma unroll
    for (int q = 0; q < 8; q++)
      *(float4*)&Ws[(4 * q + jj) * 64 + cc] = pw[q];
    // prefetch next chunk into registers (covers HBM/L2 latency under compute)
    const int kn = kc + 32;
    if (kn < kEnd) {
#pragma unroll
      for (int q = 0; q < 4; q++) {
        const int row = r0 + 8 * q + rr;
        const int col = kn + 4 * mm;
        float4 v = make_float4(0.f, 0.f, 0.f, 0.f);
        if (col + 4 <= kEnd) v = *(const float4*)&X[(size_t)row * FIN + col];
        else {
          const float* xr = &X[(size_t)row * FIN];
          if (col + 0 < kEnd) v.x = xr[col + 0];
          if (col + 1 < kEnd) v.y = xr[col + 1];
          if (col + 2 < kEnd) v.z = xr[col + 2];
          if (col + 3 < kEnd) v.w = xr[col + 3];
        }
        px[q] = v;
      }
#pragma unroll
      for (int q = 0; q < 8; q++) {
        const int j = kn + 4 * q + jj;
        pw[q] = (j < kEnd) ? *(const float4*)&W[(size_t)j * 64 + cc]
                           : make_float4(0.f, 0.f, 0.f, 0.f);
      }
    }
    // compute on staged chunk
#pragma unroll
    for (int jt = 0; jt < 8; jt++) {
      float4 xv[4];
#pragma unroll
      for (int u = 0; u < 4; u++)
        xv[u] = *(const float4*)&Xs[(4 * rr + u) * 36 + 4 * jt];
      float4 w0[4], w1[4];
#pragma unroll
      for (int j4 = 0; j4 < 4; j4++) {
        w0[j4] = *(const float4*)&Ws[(4 * jt + j4) * 64 + mm * 8];
        w1[j4] = *(const float4*)&Ws[(4 * jt + j4) * 64 + mm * 8 + 4];
      }
#pragma unroll
      for (int u = 0; u < 4; u++) {
        const float xs0 = xv[u].x, xs1 = xv[u].y, xs2 = xv[u].z, xs3 = xv[u].w;
        acc[u][0] += xs0 * w0[0].x + xs1 * w0[1].x + xs2 * w0[2].x + xs3 * w0[3].x;
        acc[u][1] += xs0 * w0[0].y + xs1 * w0[1].y + xs2 * w0[2].y + xs3 * w0[3].y;
        acc[u][2] += xs0 * w0[0].z + xs1 * w0[1].z + xs2 * w0[2].z + xs3 * w0[3].z;
        acc[u][3] += xs0 * w0[0].w + xs1 * w0[1].w + xs2 * w0[2].w + xs3 * w0[3].w;
        acc[u][4] += xs0 * w1[0].x + xs1 * w1[1].x + xs2 * w1[2].x + xs3 * w1[3].x;
        acc[u][5] += xs0 * w1[0].y + xs1 * w1[1].y + xs2 * w1[2].y + xs3 * w1[3].y;
        acc[u][6] += xs0 * w1[0].z + xs1 * w1[1].z + xs2 * w1[2].z + xs3 * w1[3].z;
        acc[u][7] += xs0 * w1[0].w + xs1 * w1[1].w + xs2 * w1[2].w + xs3 * w1[3].w;
      }
    }
  }
  float* P = Part + (size_t)split * (NROW * 64);
#pragma unroll
  for (int u = 0; u < 4; u++) {
    const int row = r0 + 4 * rr + u;
    float4 o0 = make_float4(acc[u][0], acc[u][1], acc[u][2], acc[u][3]);
    float4 o1 = make_float4(acc[u][4], acc[u][5], acc[u][6], acc[u][7]);
    *(float4*)&P[(size_t)row * 64 + mm * 8] = o0;
    *(float4*)&P[(size_t)row * 64 + mm * 8 + 4] = o1;
  }
}

// ---------------- hV = sum of 4 partials + bias ----------------
__global__ __launch_bounds__(256) void k_node_sum(const float* __restrict__ Part,
                                                  const float* __restrict__ bias,
                                                  float* __restrict__ out) {
  const int i = (blockIdx.x * 256 + threadIdx.x) * 4;
  const float4 a = *(const float4*)&Part[i];
  const float4 b = *(const float4*)&Part[1048576 + i];
  const float4 c = *(const float4*)&Part[2 * 1048576 + i];
  const float4 d = *(const float4*)&Part[3 * 1048576 + i];
  const float4 bb = *(const float4*)&bias[i & 63];
  float4 o;
  o.x = a.x + b.x + c.x + d.x + bb.x;
  o.y = a.y + b.y + c.y + d.y + bb.y;
  o.z = a.z + b.z + c.z + d.z + bb.z;
  o.w = a.w + b.w + c.w + d.w + bb.w;
  *(float4*)&out[i] = o;
}

// ---------------- edges: distances + histogram-select top-30 + E_ln precompute ----------------
__global__ __launch_bounds__(256) void k_edges(const float* __restrict__ coords,
                                               const float* __restrict__ mask,
                                               const float* __restrict__ Wee,
                                               const float* __restrict__ geln,
                                               const float* __restrict__ beln,
                                               int* __restrict__ Eidx,
                                               __half* __restrict__ Eln) {
  const int row = blockIdx.x;
  const int b = row >> 11;
  const int t = threadIdx.x;
  const int lane = t & 63, wid = t >> 6;
  __shared__ float sredf[4];
  __shared__ unsigned int hist[2048];
  __shared__ unsigned int wtot[4];
  __shared__ int s_bin, s_need;
  __shared__ int s_lcnt, s_outcnt;
  __shared__ unsigned int s_lkey[64];
  __shared__ int s_lidx[64];
  __shared__ int s_sel[64];
  __shared__ float sD[30];
  __shared__ int sJ[30];
  __shared__ float sWee[16][16];
  __shared__ float sg[16], sb[16];
  __shared__ float sRBF[30][16];

  if (t < 256) sWee[t >> 4][t & 15] = Wee[t];
  if (t < 16) { sg[t] = geln[t]; sb[t] = beln[t]; }
  if (t == 0) { s_lcnt = 0; s_outcnt = 0; }

  const float* cb = coords + (size_t)b * (L_ * 3);
  const int i = row & (L_ - 1);
  const float cix = cb[i * 3 + 0], ciy = cb[i * 3 + 1], ciz = cb[i * 3 + 2];
  const float mi = mask[row];
  const float* mb = mask + (size_t)b * L_;
  float d[8], mj[8];
  float dmax = 0.f;
#pragma unroll
  for (int u = 0; u < 8; u++) {
    int j = t + 256 * u;
    float dx = cix - cb[j * 3 + 0];
    float dy = ciy - cb[j * 3 + 1];
    float dz = ciz - cb[j * 3 + 2];
    float dist = sqrtf(dx * dx + dy * dy + dz * dz + 1e-6f);
    d[u] = dist;
    mj[u] = mb[j];
    dmax = fmaxf(dmax, dist);
  }
#pragma unroll
  for (int off = 32; off; off >>= 1) dmax = fmaxf(dmax, __shfl_xor(dmax, off, 64));
  if (lane == 0) sredf[wid] = dmax;
#pragma unroll
  for (int q = 0; q < 8; q++) hist[t * 8 + q] = 0u;
  __syncthreads();
  dmax = fmaxf(fmaxf(sredf[0], sredf[1]), fmaxf(sredf[2], sredf[3]));
  const float scale = 1024.0f / fmaxf(dmax, 1e-20f);
  float adj[8];
  int bin[8];
#pragma unroll
  for (int u = 0; u < 8; u++) {
    adj[u] = d[u] + (1.f - mi * mj[u]) * dmax;
    int bi = (int)(adj[u] * scale);
    bin[u] = bi < 2047 ? bi : 2047;
    atomicAdd(&hist[bin[u]], 1u);
  }
  __syncthreads();
  unsigned int c[8];
  unsigned int local = 0;
#pragma unroll
  for (int q = 0; q < 8; q++) { c[q] = hist[t * 8 + q]; local += c[q]; }
  unsigned int incl = local;
#pragma unroll
  for (int off = 1; off < 64; off <<= 1) {
    unsigned int v = __shfl_up(incl, off, 64);
    if (lane >= off) incl += v;
  }
  if (lane == 63) wtot[wid] = incl;
  __syncthreads();
  unsigned int excl = incl - local;
  for (int w = 0; w < wid; w++) excl += wtot[w];
  if (excl < 30u && excl + local >= 30u) {
    unsigned int run = excl;
#pragma unroll
    for (int q = 0; q < 8; q++) {
      if (run + c[q] >= 30u) { s_bin = t * 8 + q; s_need = 30 - (int)run; break; }
      run += c[q];
    }
  }
  __syncthreads();
  const int tbin = s_bin;
  int pos[8];
#pragma unroll
  for (int u = 0; u < 8; u++) {
    pos[u] = -1;
    if (bin[u] == tbin) {
      int p = atomicAdd(&s_lcnt, 1);
      if (p < 64) { s_lkey[p] = __float_as_uint(adj[u]); s_lidx[p] = t + 256 * u; pos[u] = p; }
    }
  }
  __syncthreads();
  {
    int n = s_lcnt < 64 ? s_lcnt : 64;
    if (t < n) {
      unsigned int k0 = s_lkey[t];
      int j0 = s_lidx[t];
      int r = 0;
      for (int m = 0; m < n; m++) {
        unsigned int km = s_lkey[m];
        r += (km < k0) || (km == k0 && s_lidx[m] < j0);
      }
      s_sel[t] = (r < s_need) ? 1 : 0;
    }
  }
  __syncthreads();
#pragma unroll
  for (int u = 0; u < 8; u++) {
    bool sel = (bin[u] < tbin) || (pos[u] >= 0 && s_sel[pos[u]]);
    if (sel) {
      int o = atomicAdd(&s_outcnt, 1);
      if (o < 30) { sJ[o] = t + 256 * u; sD[o] = adj[u]; }
    }
  }
  __syncthreads();
  if (t < 30) Eidx[(size_t)row * 30 + t] = sJ[t];
  for (int o = t; o < 480; o += 256) {
    int k = o >> 4, s = o & 15;
    float mu = 2.0f + (4.0f / 3.0f) * (float)s;
    float z = (sD[k] - mu) * 0.8f;
    sRBF[k][s] = __expf(-z * z);
  }
  __syncthreads();
  if (t < 240) {
    int k = t >> 3, p = t & 7;
    int c0 = p * 2, c1 = c0 + 1;
    float e0 = 0.f, e1 = 0.f;
#pragma unroll
    for (int s = 0; s < 16; s++) {
      float r = sRBF[k][s];
      e0 += r * sWee[s][c0];
      e1 += r * sWee[s][c1];
    }
    float s1 = e0 + e1, s2 = e0 * e0 + e1 * e1;
#pragma unroll
    for (int m = 1; m < 8; m <<= 1) {
      s1 += __shfl_xor(s1, m, 64);
      s2 += __shfl_xor(s2, m, 64);
    }
    float mean = s1 * (1.f / 16.f);
    float var = s2 * (1.f / 16.f) - mean * mean;
    float inv = rsqrtf(var + 1e-5f);
    Eln[(size_t)row * 480 + k * 16 + c0] = __float2half((e0 - mean) * inv * sg[c0] + sb[c0]);
    Eln[(size_t)row * 480 + k * 16 + c1] = __float2half((e1 - mean) * inv * sg[c1] + sb[c1]);
  }
}

// ---------------- generic 64x64 GEMM + bias (Q projection) ----------------
__global__ __launch_bounds__(256) void k_gemm64(const float* __restrict__ X,
                                                const float* __restrict__ W,
                                                const float* __restrict__ bias,
                                                float* __restrict__ out) {
  __shared__ float Xs[64][64];
  __shared__ float Ws[64][64];
  const int t = threadIdx.x;
  const int row0 = blockIdx.x * 64;
#pragma unroll
  for (int q = 0; q < 16; q++) {
    int i = t + 256 * q;
    int r = i >> 6, c = i & 63;
    Xs[r][c] = X[(size_t)(row0 + r) * 64 + c];
    Ws[r][c] = W[i];
  }
  __syncthreads();
  const int c = t & 63, rg = t >> 6;
  float acc[16];
#pragma unroll
  for (int u = 0; u < 16; u++) acc[u] = 0.f;
#pragma unroll
  for (int s0 = 0; s0 < 64; s0 += 4) {
    float w0 = Ws[s0][c], w1 = Ws[s0 + 1][c], w2 = Ws[s0 + 2][c], w3 = Ws[s0 + 3][c];
#pragma unroll
    for (int u = 0; u < 16; u++) {
      const float4 a = *(const float4*)&Xs[rg + 4 * u][s0];
      acc[u] += a.x * w0 + a.y * w1 + a.z * w2 + a.w * w3;
    }
  }
  const float bb = bias[c];
#pragma unroll
  for (int u = 0; u < 16; u++)
    out[(size_t)(row0 + rg + 4 * u) * 64 + c] = acc[u] + bb;
}

// ---------------- qw[row][s][h] = sum_d Q[row][h*16+d] * WK[s][h*16+d]; qbK = Q.bK ----------------
__global__ __launch_bounds__(256) void k_qw(const float* __restrict__ Q,
                                            const float* __restrict__ WK,
                                            const float* __restrict__ bK,
                                            float* __restrict__ QW,
                                            float* __restrict__ qbK) {
  __shared__ float sQ[64][64];
  __shared__ float sWK[128][64];
  const int t = threadIdx.x;
  const int row0 = blockIdx.x * 64;
#pragma unroll
  for (int q = 0; q < 16; q++) {
    int i = t + 256 * q;
    sQ[i >> 6][i & 63] = Q[(size_t)(row0 + (i >> 6)) * 64 + (i & 63)];
  }
#pragma unroll
  for (int q = 0; q < 32; q++) {
    int i = t + 256 * q;
    sWK[i >> 6][i & 63] = WK[i];
  }
  __syncthreads();
  {
    int r = t >> 2, hh = t & 3;
    float a = 0.f;
#pragma unroll
    for (int d = 0; d < 16; d++) a += sQ[r][hh * 16 + d] * bK[hh * 16 + d];
    qbK[(size_t)(row0 + r) * 4 + hh] = a;
  }
  const int h = t & 3, s2 = t >> 2;
  for (int r = 0; r < 64; r++) {
    float a0 = 0.f, a1 = 0.f;
#pragma unroll
    for (int d0 = 0; d0 < 16; d0 += 4) {
      const float4 q4 = *(const float4*)&sQ[r][h * 16 + d0];
      const float4 wa = *(const float4*)&sWK[s2][h * 16 + d0];
      const float4 wb = *(const float4*)&sWK[s2 + 64][h * 16 + d0];
      a0 += q4.x * wa.x + q4.y * wa.y + q4.z * wa.z + q4.w * wa.w;
      a1 += q4.x * wb.x + q4.y * wb.y + q4.z * wb.z + q4.w * wb.w;
    }
    QW[(size_t)(row0 + r) * 512 + s2 * 4 + h] = a0;
    QW[(size_t)(row0 + r) * 512 + (s2 + 64) * 4 + h] = a1;
  }
}

// ---------------- per-row attention core: hEV, logits, softmax, P ----------------
__global__ __launch_bounds__(256) void k_attn(
    const __half* __restrict__ Eln, const int* __restrict__ Eidx,
    const float* __restrict__ hV, const float* __restrict__ mask,
    const float* __restrict__ QWg, const float* __restrict__ qbKg,
    const float* __restrict__ Wep, const float* __restrict__ bep,
    float* __restrict__ Pg, float* __restrict__ attsum) {
  const int row = blockIdx.x;
  const int b = row >> 11;
  const int t = threadIdx.x;
  const int lane = t & 63, wid = t >> 6;
  __shared__ float sEV[30][132];
  __shared__ float sQW[4][128];
  __shared__ float sE[30][17];
  __shared__ float sWep[16][64];
  __shared__ float sbep[64];
  __shared__ float sqb[4];
  __shared__ float slog[4][32];
  __shared__ float satt[4][32];
  __shared__ float smk[32];
  __shared__ int sIdx[30];

  if (t < 64) sbep[t] = bep[t];
  for (int q = t; q < 1024; q += 256) sWep[q >> 6][q & 63] = Wep[q];
  if (t < 4) sqb[t] = qbKg[(size_t)row * 4 + t];
  if (t < 30) {
    int j = Eidx[(size_t)row * 30 + t];
    sIdx[t] = j;
    smk[t] = mask[(b << 11) + j] * mask[row];
  }
  for (int o = t; o < 480; o += 256)
    sE[o >> 4][o & 15] = __half2float(Eln[(size_t)row * 480 + o]);
#pragma unroll
  for (int q = 0; q < 2; q++) {
    int o = t + 256 * q;
    float v = QWg[(size_t)row * 512 + o];
    sQW[o & 3][o >> 2] = v;
  }
  __syncthreads();
#pragma unroll
  for (int q = 0; q < 8; q++) {
    int o = t + 256 * q;
    if (o < 1920) {
      int k = o >> 6, c = o & 63;
      float a = sbep[c];
#pragma unroll
      for (int s = 0; s < 16; s++) a += sE[k][s] * sWep[s][c];
      sEV[k][c] = a;
      sEV[k][64 + c] = hV[((size_t)(b << 11) + sIdx[k]) * 64 + c];
    }
  }
  __syncthreads();
  if (t < 240) {
    int k = t >> 3, h = (t >> 1) & 3, z = t & 1;
    float a = 0.f;
    const int s00 = z * 64;
#pragma unroll
    for (int s0 = 0; s0 < 64; s0 += 4) {
      const float4 e = *(const float4*)&sEV[k][s00 + s0];
      const float4 w = *(const float4*)&sQW[h][s00 + s0];
      a += e.x * w.x + e.y * w.y + e.z * w.z + e.w * w.w;
    }
    a += __shfl_xor(a, 1, 64);
    if (z == 0) {
      float lg = (a + sqb[h]) * 0.25f;
      if (!(smk[k] > 0.f)) lg = -3.402823466e38f;
      slog[h][k] = lg;
    }
  }
  __syncthreads();
  {
    float lg = (lane < 30) ? slog[wid][lane] : -3.402823466e38f;
    float mx = lg;
#pragma unroll
    for (int off = 32; off; off >>= 1) mx = fmaxf(mx, __shfl_xor(mx, off, 64));
    float e = (lane < 30) ? __expf(lg - mx) : 0.f;
    float den = e;
#pragma unroll
    for (int off = 32; off; off >>= 1) den += __shfl_xor(den, off, 64);
    float inv = 1.f / den;
    float av = (lane < 30) ? e * inv * smk[lane] : 0.f;
    if (lane < 30) satt[wid][lane] = av;
    float ss = av;
#pragma unroll
    for (int off = 32; off; off >>= 1) ss += __shfl_xor(ss, off, 64);
    if (lane == 0) attsum[(size_t)row * 4 + wid] = ss;
  }
  __syncthreads();
#pragma unroll
  for (int q = 0; q < 2; q++) {
    int o = t + 256 * q;
    int h = o >> 7, s = o & 127;
    float a = 0.f;
    for (int k = 0; k < 30; k++) a += satt[h][k] * sEV[k][s];
    Pg[(size_t)row * 512 + o] = a;
  }
}

// ---------------- upd = P @ WV (per-head slices) + attsum*bV ----------------
__global__ __launch_bounds__(256) void k_upd(const float* __restrict__ Pg,
                                             const float* __restrict__ ats,
                                             const float* __restrict__ WV,
                                             const float* __restrict__ bV,
                                             float* __restrict__ U) {
  __shared__ float sWV[128][64];
  __shared__ float sP[8][512];
  const int t = threadIdx.x;
  const int row0 = blockIdx.x * 8;
#pragma unroll
  for (int q = 0; q < 32; q++) {
    int i = t + 256 * q;
    sWV[i >> 6][i & 63] = WV[i];
  }
#pragma unroll
  for (int q = 0; q < 16; q++) {
    int i = t + 256 * q;
    sP[i >> 9][i & 511] = Pg[(size_t)row0 * 512 + i];
  }
  __syncthreads();
  const int c = t & 63, rg = t >> 6;
  const int h = c >> 4;
  const int r0 = rg * 2;
  float a0 = 0.f, a1 = 0.f;
#pragma unroll
  for (int s0 = 0; s0 < 128; s0 += 4) {
    float w0 = sWV[s0][c], w1 = sWV[s0 + 1][c], w2 = sWV[s0 + 2][c], w3 = sWV[s0 + 3][c];
    const float4 p0 = *(const float4*)&sP[r0][h * 128 + s0];
    const float4 p1 = *(const float4*)&sP[r0 + 1][h * 128 + s0];
    a0 += p0.x * w0 + p0.y * w1 + p0.z * w2 + p0.w * w3;
    a1 += p1.x * w0 + p1.y * w1 + p1.z * w2 + p1.w * w3;
  }
  const float bv = bV[c];
  const int grow = row0 + r0;
  U[(size_t)grow * 64 + c] = a0 + ats[(size_t)grow * 4 + h] * bv;
  U[(size_t)(grow + 1) * 64 + c] = a1 + ats[(size_t)(grow + 1) * 4 + h] * bv;
}

// ---------------- hV = LN(hV + U @ WO + bO) ----------------
__global__ __launch_bounds__(256) void k_resln(const float* __restrict__ U,
                                               const float* __restrict__ WO,
                                               const float* __restrict__ bO,
                                               const float* __restrict__ g,
                                               const float* __restrict__ bb,
                                               float* __restrict__ hV) {
  __shared__ float sUt[64][16];
  __shared__ float sW[64][64];
  __shared__ float sO[16][64];
  const int t = threadIdx.x;
  const int row0 = blockIdx.x * 16;
#pragma unroll
  for (int q = 0; q < 4; q++) {
    int i = t + 256 * q;
    int r = i >> 6, cc = i & 63;
    sUt[cc][r] = U[(size_t)(row0 + r) * 64 + cc];
  }
#pragma unroll
  for (int q = 0; q < 16; q++) {
    int i = t + 256 * q;
    sW[i >> 6][i & 63] = WO[i];
  }
  __syncthreads();
  const int c = t & 63, rg = t >> 6;
  float acc[4] = {0.f, 0.f, 0.f, 0.f};
#pragma unroll
  for (int s = 0; s < 64; s++) {
    float w = sW[s][c];
    const float4 x = *(const float4*)&sUt[s][rg * 4];
    acc[0] += x.x * w; acc[1] += x.y * w; acc[2] += x.z * w; acc[3] += x.w * w;
  }
  const float bv = bO[c];
#pragma unroll
  for (int u = 0; u < 4; u++) sO[rg * 4 + u][c] = acc[u] + bv;
  __syncthreads();
  const int lane = t & 63, wv = t >> 6;
  const float gv = g[lane], bbv = bb[lane];
  for (int r = wv; r < 16; r += 4) {
    const int row = row0 + r;
    float x = hV[(size_t)row * 64 + lane] + sO[r][lane];
    float s1 = x, s2 = x * x;
#pragma unroll
    for (int off = 32; off; off >>= 1) {
      s1 += __shfl_xor(s1, off, 64);
      s2 += __shfl_xor(s2, off, 64);
    }
    float m = s1 * (1.f / 64.f);
    float var = s2 * (1.f / 64.f) - m * m;
    float inv = rsqrtf(var + 1e-5f);
    hV[(size_t)row * 64 + lane] = (x - m) * inv * gv + bbv;
  }
}

// ---------------- T = relu(hV @ W1 + bf1) ----------------
__global__ __launch_bounds__(256) void k_ffn1(const float* __restrict__ X,
                                              const float* __restrict__ W1,
                                              const float* __restrict__ bf1,
                                              float* __restrict__ T) {
  __shared__ float sXt[64][16];
  __shared__ float sW[32][256];
  const int t = threadIdx.x;
  const int row0 = blockIdx.x * 16;
#pragma unroll
  for (int q = 0; q < 4; q++) {
    int i = t + 256 * q;
    int r = i >> 6, cc = i & 63;
    sXt[cc][r] = X[(size_t)(row0 + r) * 64 + cc];
  }
  float acc[16];
#pragma unroll
  for (int u = 0; u < 16; u++) acc[u] = 0.f;
  for (int kc = 0; kc < 64; kc += 32) {
    __syncthreads();
#pragma unroll
    for (int q = 0; q < 32; q++) {
      int i = t + 256 * q;
      sW[i >> 8][i & 255] = W1[(size_t)(kc + (i >> 8)) * 256 + (i & 255)];
    }
    __syncthreads();
#pragma unroll
    for (int s = 0; s < 32; s++) {
      float w = sW[s][t];
      const float4 x0 = *(const float4*)&sXt[kc + s][0];
      const float4 x1 = *(const float4*)&sXt[kc + s][4];
      const float4 x2 = *(const float4*)&sXt[kc + s][8];
      const float4 x3 = *(const float4*)&sXt[kc + s][12];
      acc[0] += x0.x * w; acc[1] += x0.y * w; acc[2] += x0.z * w; acc[3] += x0.w * w;
      acc[4] += x1.x * w; acc[5] += x1.y * w; acc[6] += x1.z * w; acc[7] += x1.w * w;
      acc[8] += x2.x * w; acc[9] += x2.y * w; acc[10] += x2.z * w; acc[11] += x2.w * w;
      acc[12] += x3.x * w; acc[13] += x3.y * w; acc[14] += x3.z * w; acc[15] += x3.w * w;
    }
  }
  const float bv = bf1[t];
#pragma unroll
  for (int r = 0; r < 16; r++)
    T[(size_t)(row0 + r) * 256 + t] = fmaxf(acc[r] + bv, 0.f);
}

// ---------------- hV = LN(hV + T @ W2 + bf2) * mask ----------------
__global__ __launch_bounds__(256) void k_ffn2(const float* __restrict__ T,
                                              const float* __restrict__ W2,
                                              const float* __restrict__ bf2,
                                              const float* __restrict__ g,
                                              const float* __restrict__ bb,
                                              const float* __restrict__ mask,
                                              float* __restrict__ hV) {
  __shared__ float sTt[64][16];
  __shared__ float sW[64][64];
  __shared__ float sO[16][64];
  const int t = threadIdx.x;
  const int row0 = blockIdx.x * 16;
  const int c = t & 63, rg = t >> 6;
  float acc[4] = {0.f, 0.f, 0.f, 0.f};
  for (int kc = 0; kc < 256; kc += 64) {
    __syncthreads();
#pragma unroll
    for (int q = 0; q < 4; q++) {
      int i = t + 256 * q;
      int r = i >> 6, cc = i & 63;
      sTt[cc][r] = T[(size_t)(row0 + r) * 256 + kc + cc];
    }
#pragma unroll
    for (int q = 0; q < 16; q++) {
      int i = t + 256 * q;
      sW[i >> 6][i & 63] = W2[(size_t)(kc + (i >> 6)) * 64 + (i & 63)];
    }
    __syncthreads();
#pragma unroll
    for (int s = 0; s < 64; s++) {
      float w = sW[s][c];
      const float4 x = *(const float4*)&sTt[s][rg * 4];
      acc[0] += x.x * w; acc[1] += x.y * w; acc[2] += x.z * w; acc[3] += x.w * w;
    }
  }
  const float bv = bf2[c];
#pragma unroll
  for (int u = 0; u < 4; u++) sO[rg * 4 + u][c] = acc[u] + bv;
  __syncthreads();
  const int lane = t & 63, wv = t >> 6;
  const float gv = g[lane], bbv = bb[lane];
  for (int r = wv; r < 16; r += 4) {
    const int row = row0 + r;
    float x = hV[(size_t)row * 64 + lane] + sO[r][lane];
    float s1 = x, s2 = x * x;
#pragma unroll
    for (int off = 32; off; off >>= 1) {
      s1 += __shfl_xor(s1, off, 64);
      s2 += __shfl_xor(s2, off, 64);
    }
    float m = s1 * (1.f / 64.f);
    float var = s2 * (1.f / 64.f) - m * m;
    float inv = rsqrtf(var + 1e-5f);
    float y = (x - m) * inv * gv + bbv;
    hV[(size_t)row * 64 + lane] = y * mask[row];
  }
}

// ---------------- out = hV @ W_out + b_out ----------------
__global__ __launch_bounds__(256) void k_out(const float* __restrict__ hV,
                                             const float* __restrict__ Wo,
                                             const float* __restrict__ bo,
                                             float* __restrict__ out) {
  const int t = threadIdx.x;
  const int lane = t & 63, wv = t >> 6;
  const int row = blockIdx.x * 4 + wv;
  float v = hV[(size_t)row * 64 + lane] * Wo[lane];
#pragma unroll
  for (int off = 32; off; off >>= 1) v += __shfl_xor(v, off, 64);
  if (lane == 0) out[row] = v + bo[0];
}

extern "C" void kernel_launch(void* const* d_in, const int* in_sizes, int n_in,
                              void* d_out, int out_size, void* d_ws, size_t ws_size,
                              hipStream_t stream) {
  const float* coords = (const float*)d_in[0];
  const float* nodef = (const float*)d_in[1];
  const float* mask = (const float*)d_in[2];
  const float* W_node = (const float*)d_in[3];
  const float* b_node = (const float*)d_in[4];
  const float* W_ee = (const float*)d_in[5];
  const float* g_eln = (const float*)d_in[6];
  const float* b_eln = (const float*)d_in[7];
  const float* W_ep = (const float*)d_in[8];
  const float* b_ep = (const float*)d_in[9];
  const float* WQ = (const float*)d_in[10];
  const float* bQ = (const float*)d_in[11];
  const float* WK = (const float*)d_in[12];
  const float* bK = (const float*)d_in[13];
  const float* WV = (const float*)d_in[14];
  const float* bV = (const float*)d_in[15];
  const float* WO = (const float*)d_in[16];
  const float* bO = (const float*)d_in[17];
  const float* g1 = (const float*)d_in[18];
  const float* b1 = (const float*)d_in[19];
  const float* W1 = (const float*)d_in[20];
  const float* bf1 = (const float*)d_in[21];
  const float* W2 = (const float*)d_in[22];
  const float* bf2 = (const float*)d_in[23];
  const float* g2 = (const float*)d_in[24];
  const float* b2 = (const float*)d_in[25];
  const float* W_out = (const float*)d_in[26];
  const float* b_out = (const float*)d_in[27];

  float* ws = (float*)d_ws;
  float* hV = ws;                          // 1,048,576 f
  float* Qb = hV + 1048576;                // 1,048,576 f  (Q, later upd)
  float* QW = Qb + 1048576;                // 8,388,608 f  (also aliased as Tb)
  float* Pg = QW + 8388608;                // 8,388,608 f  (also aliased as Part)
  float* qbK = Pg + 8388608;               // 65,536 f
  float* ats = qbK + 65536;                // 65,536 f
  int* Eidx = (int*)(ats + 65536);         // 491,520 i
  __half* Eln = (__half*)(Eidx + 491520);  // 7,864,320 h   (total ~93.7 MB)
  float* Tb = QW;                          // alias: lifetime disjoint from QW
  float* Part = Pg;                        // alias: k_node partials (4 x 1,048,576 f)

  k_node_part<<<512, 256, 0, stream>>>(nodef, W_node, Part);
  k_node_sum<<<1024, 256, 0, stream>>>(Part, b_node, hV);
  k_edges<<<16384, 256, 0, stream>>>(coords, mask, W_ee, g_eln, b_eln, Eidx, Eln);
  for (int l = 0; l < 4; l++) {
    k_gemm64<<<256, 256, 0, stream>>>(hV, WQ + l * 4096, bQ + l * 64, Qb);
    k_qw<<<256, 256, 0, stream>>>(Qb, WK + l * 8192, bK + l * 64, QW, qbK);
    k_attn<<<16384, 256, 0, stream>>>(Eln, Eidx, hV, mask, QW, qbK,
                                      W_ep, b_ep, Pg, ats);
    k_upd<<<2048, 256, 0, stream>>>(Pg, ats, WV + l * 8192, bV + l * 64, Qb);
    k_resln<<<1024, 256, 0, stream>>>(Qb, WO + l * 4096, bO + l * 64,
                                      g1 + l * 64, b1 + l * 64, hV);
    k_ffn1<<<1024, 256, 0, stream>>>(hV, W1 + l * 16384, bf1 + l * 256, Tb);
    k_ffn2<<<1024, 256, 0, stream>>>(Tb, W2 + l * 16384, bf2 + l * 64,
                                     g2 + l * 64, b2 + l * 64, mask, hV);
  }
  k_out<<<4096, 256, 0, stream>>>(hV, W_out, b_out, (float*)d_out);
}

// Round 4
// 1260.460 us; speedup vs baseline: 1.3349x; 1.1725x over previous
//
#include <hip/hip_runtime.h>
#include <hip/hip_fp16.h>

#define L_ 2048
#define NROW 16384
#define FIN 1038

// ---------------- node embedding part: Part[split] = X[:, ks:ke] @ W[ks:ke, :] ----------------
// Double-buffered LDS, K-chunk 16, tiny register prefetch (12 VGPRs) -> no spill.
// Block: 128 rows x 64 cols; thread micro-tile 4 rows x 8 cols.
__global__ __launch_bounds__(256) void k_node_part(const float* __restrict__ X,
                                                   const float* __restrict__ W,
                                                   float* __restrict__ Part) {
  const int rb = blockIdx.x >> 2;
  const int split = blockIdx.x & 3;
  const int kStart = split * 260;
  const int kEnd = (split == 3) ? FIN : (kStart + 260);
  const int t = threadIdx.x;
  const int row0 = rb * 128;
  __shared__ float Xs[2][16][132];  // [buf][k][row] (K-transposed)
  __shared__ float Ws[2][16][64];   // [buf][k][col]
  const int ri = t >> 3;            // 0..31 row-group (4 rows)
  const int ci = t & 7;             // 0..7  col-group (8 cols)
  const int sxr = t >> 2;           // X stage: row 0..63 (+64)
  const int sxk = (t & 3) * 4;      // X stage: k sub-offset 0,4,8,12
  const int swr = t >> 4;           // W stage: k row 0..15
  const int swc = (t & 15) * 4;     // W stage: col 0..60

  float acc[4][8];
#pragma unroll
  for (int u = 0; u < 4; u++)
#pragma unroll
    for (int v = 0; v < 8; v++) acc[u][v] = 0.f;

  float4 px0, px1, pwv;

#define LOADX(dst, kc, rsub)                                            \
  {                                                                     \
    const int col = (kc) + sxk;                                         \
    const float* xr = &X[(size_t)(row0 + sxr + 64 * (rsub)) * FIN];     \
    float4 v = make_float4(0.f, 0.f, 0.f, 0.f);                         \
    if (col + 4 <= kEnd) v = *(const float4*)&xr[col];                  \
    else {                                                              \
      if (col + 0 < kEnd) v.x = xr[col + 0];                            \
      if (col + 1 < kEnd) v.y = xr[col + 1];                            \
      if (col + 2 < kEnd) v.z = xr[col + 2];                            \
      if (col + 3 < kEnd) v.w = xr[col + 3];                            \
    }                                                                   \
    dst = v;                                                            \
  }
#define LOADW(dst, kc)                                                  \
  {                                                                     \
    const int j = (kc) + swr;                                           \
    dst = (j < kEnd) ? *(const float4*)&W[(size_t)j * 64 + swc]         \
                     : make_float4(0.f, 0.f, 0.f, 0.f);                 \
  }

  LOADX(px0, kStart, 0);
  LOADX(px1, kStart, 1);
  LOADW(pwv, kStart);

  int buf = 0;
  for (int kc = kStart; kc < kEnd; kc += 16) {
    // stage prefetched chunk into LDS[buf]
    Xs[buf][sxk + 0][sxr] = px0.x;
    Xs[buf][sxk + 1][sxr] = px0.y;
    Xs[buf][sxk + 2][sxr] = px0.z;
    Xs[buf][sxk + 3][sxr] = px0.w;
    Xs[buf][sxk + 0][64 + sxr] = px1.x;
    Xs[buf][sxk + 1][64 + sxr] = px1.y;
    Xs[buf][sxk + 2][64 + sxr] = px1.z;
    Xs[buf][sxk + 3][64 + sxr] = px1.w;
    *(float4*)&Ws[buf][swr][swc] = pwv;
    __syncthreads();
    // prefetch next chunk (covers HBM latency under compute)
    const int kn = kc + 16;
    if (kn < kEnd) {
      LOADX(px0, kn, 0);
      LOADX(px1, kn, 1);
      LOADW(pwv, kn);
    }
    // compute 16 k-steps from LDS[buf]
#pragma unroll
    for (int k = 0; k < 16; k++) {
      const float4 xv = *(const float4*)&Xs[buf][k][4 * ri];
      const float4 w0 = *(const float4*)&Ws[buf][k][8 * ci];
      const float4 w1 = *(const float4*)&Ws[buf][k][8 * ci + 4];
      const float xr_[4] = {xv.x, xv.y, xv.z, xv.w};
      const float wc_[8] = {w0.x, w0.y, w0.z, w0.w, w1.x, w1.y, w1.z, w1.w};
#pragma unroll
      for (int u = 0; u < 4; u++)
#pragma unroll
        for (int v = 0; v < 8; v++) acc[u][v] += xr_[u] * wc_[v];
    }
    buf ^= 1;
  }
#undef LOADX
#undef LOADW

  float* P = Part + (size_t)split * (NROW * 64);
#pragma unroll
  for (int u = 0; u < 4; u++) {
    const int row = row0 + 4 * ri + u;
    *(float4*)&P[(size_t)row * 64 + 8 * ci] =
        make_float4(acc[u][0], acc[u][1], acc[u][2], acc[u][3]);
    *(float4*)&P[(size_t)row * 64 + 8 * ci + 4] =
        make_float4(acc[u][4], acc[u][5], acc[u][6], acc[u][7]);
  }
}

// ---------------- hV = sum of 4 partials + bias ----------------
__global__ __launch_bounds__(256) void k_node_sum(const float* __restrict__ Part,
                                                  const float* __restrict__ bias,
                                                  float* __restrict__ out) {
  const int i = (blockIdx.x * 256 + threadIdx.x) * 4;
  const float4 a = *(const float4*)&Part[i];
  const float4 b = *(const float4*)&Part[1048576 + i];
  const float4 c = *(const float4*)&Part[2 * 1048576 + i];
  const float4 d = *(const float4*)&Part[3 * 1048576 + i];
  const float4 bb = *(const float4*)&bias[i & 63];
  float4 o;
  o.x = a.x + b.x + c.x + d.x + bb.x;
  o.y = a.y + b.y + c.y + d.y + bb.y;
  o.z = a.z + b.z + c.z + d.z + bb.z;
  o.w = a.w + b.w + c.w + d.w + bb.w;
  *(float4*)&out[i] = o;
}

// ---------------- edges: distances + histogram-select top-30 + E_ln precompute ----------------
__global__ __launch_bounds__(256) void k_edges(const float* __restrict__ coords,
                                               const float* __restrict__ mask,
                                               const float* __restrict__ Wee,
                                               const float* __restrict__ geln,
                                               const float* __restrict__ beln,
                                               int* __restrict__ Eidx,
                                               __half* __restrict__ Eln) {
  const int row = blockIdx.x;
  const int b = row >> 11;
  const int t = threadIdx.x;
  const int lane = t & 63, wid = t >> 6;
  __shared__ float sredf[4];
  __shared__ unsigned int hist[2048];
  __shared__ unsigned int wtot[4];
  __shared__ int s_bin, s_need;
  __shared__ int s_lcnt, s_outcnt;
  __shared__ unsigned int s_lkey[64];
  __shared__ int s_lidx[64];
  __shared__ int s_sel[64];
  __shared__ float sD[30];
  __shared__ int sJ[30];
  __shared__ float sWee[16][16];
  __shared__ float sg[16], sb[16];
  __shared__ float sRBF[30][16];

  if (t < 256) sWee[t >> 4][t & 15] = Wee[t];
  if (t < 16) { sg[t] = geln[t]; sb[t] = beln[t]; }
  if (t == 0) { s_lcnt = 0; s_outcnt = 0; }

  const float* cb = coords + (size_t)b * (L_ * 3);
  const int i = row & (L_ - 1);
  const float cix = cb[i * 3 + 0], ciy = cb[i * 3 + 1], ciz = cb[i * 3 + 2];
  const float mi = mask[row];
  const float* mb = mask + (size_t)b * L_;
  float d[8], mj[8];
  float dmax = 0.f;
#pragma unroll
  for (int u = 0; u < 8; u++) {
    int j = t + 256 * u;
    float dx = cix - cb[j * 3 + 0];
    float dy = ciy - cb[j * 3 + 1];
    float dz = ciz - cb[j * 3 + 2];
    float dist = sqrtf(dx * dx + dy * dy + dz * dz + 1e-6f);
    d[u] = dist;
    mj[u] = mb[j];
    dmax = fmaxf(dmax, dist);
  }
#pragma unroll
  for (int off = 32; off; off >>= 1) dmax = fmaxf(dmax, __shfl_xor(dmax, off, 64));
  if (lane == 0) sredf[wid] = dmax;
#pragma unroll
  for (int q = 0; q < 8; q++) hist[t * 8 + q] = 0u;
  __syncthreads();
  dmax = fmaxf(fmaxf(sredf[0], sredf[1]), fmaxf(sredf[2], sredf[3]));
  const float scale = 1024.0f / fmaxf(dmax, 1e-20f);
  float adj[8];
  int bin[8];
#pragma unroll
  for (int u = 0; u < 8; u++) {
    adj[u] = d[u] + (1.f - mi * mj[u]) * dmax;
    int bi = (int)(adj[u] * scale);
    bin[u] = bi < 2047 ? bi : 2047;
    atomicAdd(&hist[bin[u]], 1u);
  }
  __syncthreads();
  unsigned int c[8];
  unsigned int local = 0;
#pragma unroll
  for (int q = 0; q < 8; q++) { c[q] = hist[t * 8 + q]; local += c[q]; }
  unsigned int incl = local;
#pragma unroll
  for (int off = 1; off < 64; off <<= 1) {
    unsigned int v = __shfl_up(incl, off, 64);
    if (lane >= off) incl += v;
  }
  if (lane == 63) wtot[wid] = incl;
  __syncthreads();
  unsigned int excl = incl - local;
  for (int w = 0; w < wid; w++) excl += wtot[w];
  if (excl < 30u && excl + local >= 30u) {
    unsigned int run = excl;
#pragma unroll
    for (int q = 0; q < 8; q++) {
      if (run + c[q] >= 30u) { s_bin = t * 8 + q; s_need = 30 - (int)run; break; }
      run += c[q];
    }
  }
  __syncthreads();
  const int tbin = s_bin;
  int pos[8];
#pragma unroll
  for (int u = 0; u < 8; u++) {
    pos[u] = -1;
    if (bin[u] == tbin) {
      int p = atomicAdd(&s_lcnt, 1);
      if (p < 64) { s_lkey[p] = __float_as_uint(adj[u]); s_lidx[p] = t + 256 * u; pos[u] = p; }
    }
  }
  __syncthreads();
  {
    int n = s_lcnt < 64 ? s_lcnt : 64;
    if (t < n) {
      unsigned int k0 = s_lkey[t];
      int j0 = s_lidx[t];
      int r = 0;
      for (int m = 0; m < n; m++) {
        unsigned int km = s_lkey[m];
        r += (km < k0) || (km == k0 && s_lidx[m] < j0);
      }
      s_sel[t] = (r < s_need) ? 1 : 0;
    }
  }
  __syncthreads();
#pragma unroll
  for (int u = 0; u < 8; u++) {
    bool sel = (bin[u] < tbin) || (pos[u] >= 0 && s_sel[pos[u]]);
    if (sel) {
      int o = atomicAdd(&s_outcnt, 1);
      if (o < 30) { sJ[o] = t + 256 * u; sD[o] = adj[u]; }
    }
  }
  __syncthreads();
  if (t < 30) Eidx[(size_t)row * 30 + t] = sJ[t];
  for (int o = t; o < 480; o += 256) {
    int k = o >> 4, s = o & 15;
    float mu = 2.0f + (4.0f / 3.0f) * (float)s;
    float z = (sD[k] - mu) * 0.8f;
    sRBF[k][s] = __expf(-z * z);
  }
  __syncthreads();
  if (t < 240) {
    int k = t >> 3, p = t & 7;
    int c0 = p * 2, c1 = c0 + 1;
    float e0 = 0.f, e1 = 0.f;
#pragma unroll
    for (int s = 0; s < 16; s++) {
      float r = sRBF[k][s];
      e0 += r * sWee[s][c0];
      e1 += r * sWee[s][c1];
    }
    float s1 = e0 + e1, s2 = e0 * e0 + e1 * e1;
#pragma unroll
    for (int m = 1; m < 8; m <<= 1) {
      s1 += __shfl_xor(s1, m, 64);
      s2 += __shfl_xor(s2, m, 64);
    }
    float mean = s1 * (1.f / 16.f);
    float var = s2 * (1.f / 16.f) - mean * mean;
    float inv = rsqrtf(var + 1e-5f);
    Eln[(size_t)row * 480 + k * 16 + c0] = __float2half((e0 - mean) * inv * sg[c0] + sb[c0]);
    Eln[(size_t)row * 480 + k * 16 + c1] = __float2half((e1 - mean) * inv * sg[c1] + sb[c1]);
  }
}

// ---------------- generic 64x64 GEMM + bias (Q projection) ----------------
__global__ __launch_bounds__(256) void k_gemm64(const float* __restrict__ X,
                                                const float* __restrict__ W,
                                                const float* __restrict__ bias,
                                                float* __restrict__ out) {
  __shared__ float Xs[64][64];
  __shared__ float Ws[64][64];
  const int t = threadIdx.x;
  const int row0 = blockIdx.x * 64;
#pragma unroll
  for (int q = 0; q < 16; q++) {
    int i = t + 256 * q;
    int r = i >> 6, c = i & 63;
    Xs[r][c] = X[(size_t)(row0 + r) * 64 + c];
    Ws[r][c] = W[i];
  }
  __syncthreads();
  const int c = t & 63, rg = t >> 6;
  float acc[16];
#pragma unroll
  for (int u = 0; u < 16; u++) acc[u] = 0.f;
#pragma unroll
  for (int s0 = 0; s0 < 64; s0 += 4) {
    float w0 = Ws[s0][c], w1 = Ws[s0 + 1][c], w2 = Ws[s0 + 2][c], w3 = Ws[s0 + 3][c];
#pragma unroll
    for (int u = 0; u < 16; u++) {
      const float4 a = *(const float4*)&Xs[rg + 4 * u][s0];
      acc[u] += a.x * w0 + a.y * w1 + a.z * w2 + a.w * w3;
    }
  }
  const float bb = bias[c];
#pragma unroll
  for (int u = 0; u < 16; u++)
    out[(size_t)(row0 + rg + 4 * u) * 64 + c] = acc[u] + bb;
}

// ---------------- qw[row][s][h] = sum_d Q[row][h*16+d] * WK[s][h*16+d]; qbK = Q.bK ----------------
__global__ __launch_bounds__(256) void k_qw(const float* __restrict__ Q,
                                            const float* __restrict__ WK,
                                            const float* __restrict__ bK,
                                            float* __restrict__ QW,
                                            float* __restrict__ qbK) {
  __shared__ float sQ[64][64];
  __shared__ float sWK[128][64];
  const int t = threadIdx.x;
  const int row0 = blockIdx.x * 64;
#pragma unroll
  for (int q = 0; q < 16; q++) {
    int i = t + 256 * q;
    sQ[i >> 6][i & 63] = Q[(size_t)(row0 + (i >> 6)) * 64 + (i & 63)];
  }
#pragma unroll
  for (int q = 0; q < 32; q++) {
    int i = t + 256 * q;
    sWK[i >> 6][i & 63] = WK[i];
  }
  __syncthreads();
  {
    int r = t >> 2, hh = t & 3;
    float a = 0.f;
#pragma unroll
    for (int d = 0; d < 16; d++) a += sQ[r][hh * 16 + d] * bK[hh * 16 + d];
    qbK[(size_t)(row0 + r) * 4 + hh] = a;
  }
  const int h = t & 3, s2 = t >> 2;
  for (int r = 0; r < 64; r++) {
    float a0 = 0.f, a1 = 0.f;
#pragma unroll
    for (int d0 = 0; d0 < 16; d0 += 4) {
      const float4 q4 = *(const float4*)&sQ[r][h * 16 + d0];
      const float4 wa = *(const float4*)&sWK[s2][h * 16 + d0];
      const float4 wb = *(const float4*)&sWK[s2 + 64][h * 16 + d0];
      a0 += q4.x * wa.x + q4.y * wa.y + q4.z * wa.z + q4.w * wa.w;
      a1 += q4.x * wb.x + q4.y * wb.y + q4.z * wb.z + q4.w * wb.w;
    }
    QW[(size_t)(row0 + r) * 512 + s2 * 4 + h] = a0;
    QW[(size_t)(row0 + r) * 512 + (s2 + 64) * 4 + h] = a1;
  }
}

// ---------------- per-row attention core: hEV, logits, softmax, P ----------------
__global__ __launch_bounds__(256) void k_attn(
    const __half* __restrict__ Eln, const int* __restrict__ Eidx,
    const float* __restrict__ hV, const float* __restrict__ mask,
    const float* __restrict__ QWg, const float* __restrict__ qbKg,
    const float* __restrict__ Wep, const float* __restrict__ bep,
    float* __restrict__ Pg, float* __restrict__ attsum) {
  const int row = blockIdx.x;
  const int b = row >> 11;
  const int t = threadIdx.x;
  const int lane = t & 63, wid = t >> 6;
  __shared__ float sEV[30][132];
  __shared__ float sQW[4][128];
  __shared__ float sE[30][17];
  __shared__ float sWep[16][64];
  __shared__ float sbep[64];
  __shared__ float sqb[4];
  __shared__ float slog[4][32];
  __shared__ float satt[4][32];
  __shared__ float smk[32];
  __shared__ int sIdx[30];

  if (t < 64) sbep[t] = bep[t];
  for (int q = t; q < 1024; q += 256) sWep[q >> 6][q & 63] = Wep[q];
  if (t < 4) sqb[t] = qbKg[(size_t)row * 4 + t];
  if (t < 30) {
    int j = Eidx[(size_t)row * 30 + t];
    sIdx[t] = j;
    smk[t] = mask[(b << 11) + j] * mask[row];
  }
  for (int o = t; o < 480; o += 256)
    sE[o >> 4][o & 15] = __half2float(Eln[(size_t)row * 480 + o]);
#pragma unroll
  for (int q = 0; q < 2; q++) {
    int o = t + 256 * q;
    float v = QWg[(size_t)row * 512 + o];
    sQW[o & 3][o >> 2] = v;
  }
  __syncthreads();
#pragma unroll
  for (int q = 0; q < 8; q++) {
    int o = t + 256 * q;
    if (o < 1920) {
      int k = o >> 6, c = o & 63;
      float a = sbep[c];
#pragma unroll
      for (int s = 0; s < 16; s++) a += sE[k][s] * sWep[s][c];
      sEV[k][c] = a;
      sEV[k][64 + c] = hV[((size_t)(b << 11) + sIdx[k]) * 64 + c];
    }
  }
  __syncthreads();
  if (t < 240) {
    int k = t >> 3, h = (t >> 1) & 3, z = t & 1;
    float a = 0.f;
    const int s00 = z * 64;
#pragma unroll
    for (int s0 = 0; s0 < 64; s0 += 4) {
      const float4 e = *(const float4*)&sEV[k][s00 + s0];
      const float4 w = *(const float4*)&sQW[h][s00 + s0];
      a += e.x * w.x + e.y * w.y + e.z * w.z + e.w * w.w;
    }
    a += __shfl_xor(a, 1, 64);
    if (z == 0) {
      float lg = (a + sqb[h]) * 0.25f;
      if (!(smk[k] > 0.f)) lg = -3.402823466e38f;
      slog[h][k] = lg;
    }
  }
  __syncthreads();
  {
    float lg = (lane < 30) ? slog[wid][lane] : -3.402823466e38f;
    float mx = lg;
#pragma unroll
    for (int off = 32; off; off >>= 1) mx = fmaxf(mx, __shfl_xor(mx, off, 64));
    float e = (lane < 30) ? __expf(lg - mx) : 0.f;
    float den = e;
#pragma unroll
    for (int off = 32; off; off >>= 1) den += __shfl_xor(den, off, 64);
    float inv = 1.f / den;
    float av = (lane < 30) ? e * inv * smk[lane] : 0.f;
    if (lane < 30) satt[wid][lane] = av;
    float ss = av;
#pragma unroll
    for (int off = 32; off; off >>= 1) ss += __shfl_xor(ss, off, 64);
    if (lane == 0) attsum[(size_t)row * 4 + wid] = ss;
  }
  __syncthreads();
#pragma unroll
  for (int q = 0; q < 2; q++) {
    int o = t + 256 * q;
    int h = o >> 7, s = o & 127;
    float a = 0.f;
    for (int k = 0; k < 30; k++) a += satt[h][k] * sEV[k][s];
    Pg[(size_t)row * 512 + o] = a;
  }
}

// ---------------- upd = P @ WV (per-head slices) + attsum*bV ----------------
__global__ __launch_bounds__(256) void k_upd(const float* __restrict__ Pg,
                                             const float* __restrict__ ats,
                                             const float* __restrict__ WV,
                                             const float* __restrict__ bV,
                                             float* __restrict__ U) {
  __shared__ float sWV[128][64];
  __shared__ float sP[8][512];
  const int t = threadIdx.x;
  const int row0 = blockIdx.x * 8;
#pragma unroll
  for (int q = 0; q < 32; q++) {
    int i = t + 256 * q;
    sWV[i >> 6][i & 63] = WV[i];
  }
#pragma unroll
  for (int q = 0; q < 16; q++) {
    int i = t + 256 * q;
    sP[i >> 9][i & 511] = Pg[(size_t)row0 * 512 + i];
  }
  __syncthreads();
  const int c = t & 63, rg = t >> 6;
  const int h = c >> 4;
  const int r0 = rg * 2;
  float a0 = 0.f, a1 = 0.f;
#pragma unroll
  for (int s0 = 0; s0 < 128; s0 += 4) {
    float w0 = sWV[s0][c], w1 = sWV[s0 + 1][c], w2 = sWV[s0 + 2][c], w3 = sWV[s0 + 3][c];
    const float4 p0 = *(const float4*)&sP[r0][h * 128 + s0];
    const float4 p1 = *(const float4*)&sP[r0 + 1][h * 128 + s0];
    a0 += p0.x * w0 + p0.y * w1 + p0.z * w2 + p0.w * w3;
    a1 += p1.x * w0 + p1.y * w1 + p1.z * w2 + p1.w * w3;
  }
  const float bv = bV[c];
  const int grow = row0 + r0;
  U[(size_t)grow * 64 + c] = a0 + ats[(size_t)grow * 4 + h] * bv;
  U[(size_t)(grow + 1) * 64 + c] = a1 + ats[(size_t)(grow + 1) * 4 + h] * bv;
}

// ---------------- hV = LN(hV + U @ WO + bO) ----------------
__global__ __launch_bounds__(256) void k_resln(const float* __restrict__ U,
                                               const float* __restrict__ WO,
                                               const float* __restrict__ bO,
                                               const float* __restrict__ g,
                                               const float* __restrict__ bb,
                                               float* __restrict__ hV) {
  __shared__ float sUt[64][16];
  __shared__ float sW[64][64];
  __shared__ float sO[16][64];
  const int t = threadIdx.x;
  const int row0 = blockIdx.x * 16;
#pragma unroll
  for (int q = 0; q < 4; q++) {
    int i = t + 256 * q;
    int r = i >> 6, cc = i & 63;
    sUt[cc][r] = U[(size_t)(row0 + r) * 64 + cc];
  }
#pragma unroll
  for (int q = 0; q < 16; q++) {
    int i = t + 256 * q;
    sW[i >> 6][i & 63] = WO[i];
  }
  __syncthreads();
  const int c = t & 63, rg = t >> 6;
  float acc[4] = {0.f, 0.f, 0.f, 0.f};
#pragma unroll
  for (int s = 0; s < 64; s++) {
    float w = sW[s][c];
    const float4 x = *(const float4*)&sUt[s][rg * 4];
    acc[0] += x.x * w; acc[1] += x.y * w; acc[2] += x.z * w; acc[3] += x.w * w;
  }
  const float bv = bO[c];
#pragma unroll
  for (int u = 0; u < 4; u++) sO[rg * 4 + u][c] = acc[u] + bv;
  __syncthreads();
  const int lane = t & 63, wv = t >> 6;
  const float gv = g[lane], bbv = bb[lane];
  for (int r = wv; r < 16; r += 4) {
    const int row = row0 + r;
    float x = hV[(size_t)row * 64 + lane] + sO[r][lane];
    float s1 = x, s2 = x * x;
#pragma unroll
    for (int off = 32; off; off >>= 1) {
      s1 += __shfl_xor(s1, off, 64);
      s2 += __shfl_xor(s2, off, 64);
    }
    float m = s1 * (1.f / 64.f);
    float var = s2 * (1.f / 64.f) - m * m;
    float inv = rsqrtf(var + 1e-5f);
    hV[(size_t)row * 64 + lane] = (x - m) * inv * gv + bbv;
  }
}

// ---------------- T = relu(hV @ W1 + bf1) ----------------
__global__ __launch_bounds__(256) void k_ffn1(const float* __restrict__ X,
                                              const float* __restrict__ W1,
                                              const float* __restrict__ bf1,
                                              float* __restrict__ T) {
  __shared__ float sXt[64][16];
  __shared__ float sW[32][256];
  const int t = threadIdx.x;
  const int row0 = blockIdx.x * 16;
#pragma unroll
  for (int q = 0; q < 4; q++) {
    int i = t + 256 * q;
    int r = i >> 6, cc = i & 63;
    sXt[cc][r] = X[(size_t)(row0 + r) * 64 + cc];
  }
  float acc[16];
#pragma unroll
  for (int u = 0; u < 16; u++) acc[u] = 0.f;
  for (int kc = 0; kc < 64; kc += 32) {
    __syncthreads();
#pragma unroll
    for (int q = 0; q < 32; q++) {
      int i = t + 256 * q;
      sW[i >> 8][i & 255] = W1[(size_t)(kc + (i >> 8)) * 256 + (i & 255)];
    }
    __syncthreads();
#pragma unroll
    for (int s = 0; s < 32; s++) {
      float w = sW[s][t];
      const float4 x0 = *(const float4*)&sXt[kc + s][0];
      const float4 x1 = *(const float4*)&sXt[kc + s][4];
      const float4 x2 = *(const float4*)&sXt[kc + s][8];
      const float4 x3 = *(const float4*)&sXt[kc + s][12];
      acc[0] += x0.x * w; acc[1] += x0.y * w; acc[2] += x0.z * w; acc[3] += x0.w * w;
      acc[4] += x1.x * w; acc[5] += x1.y * w; acc[6] += x1.z * w; acc[7] += x1.w * w;
      acc[8] += x2.x * w; acc[9] += x2.y * w; acc[10] += x2.z * w; acc[11] += x2.w * w;
      acc[12] += x3.x * w; acc[13] += x3.y * w; acc[14] += x3.z * w; acc[15] += x3.w * w;
    }
  }
  const float bv = bf1[t];
#pragma unroll
  for (int r = 0; r < 16; r++)
    T[(size_t)(row0 + r) * 256 + t] = fmaxf(acc[r] + bv, 0.f);
}

// ---------------- hV = LN(hV + T @ W2 + bf2) * mask ----------------
__global__ __launch_bounds__(256) void k_ffn2(const float* __restrict__ T,
                                              const float* __restrict__ W2,
                                              const float* __restrict__ bf2,
                                              const float* __restrict__ g,
                                              const float* __restrict__ bb,
                                              const float* __restrict__ mask,
                                              float* __restrict__ hV) {
  __shared__ float sTt[64][16];
  __shared__ float sW[64][64];
  __shared__ float sO[16][64];
  const int t = threadIdx.x;
  const int row0 = blockIdx.x * 16;
  const int c = t & 63, rg = t >> 6;
  float acc[4] = {0.f, 0.f, 0.f, 0.f};
  for (int kc = 0; kc < 256; kc += 64) {
    __syncthreads();
#pragma unroll
    for (int q = 0; q < 4; q++) {
      int i = t + 256 * q;
      int r = i >> 6, cc = i & 63;
      sTt[cc][r] = T[(size_t)(row0 + r) * 256 + kc + cc];
    }
#pragma unroll
    for (int q = 0; q < 16; q++) {
      int i = t + 256 * q;
      sW[i >> 6][i & 63] = W2[(size_t)(kc + (i >> 6)) * 64 + (i & 63)];
    }
    __syncthreads();
#pragma unroll
    for (int s = 0; s < 64; s++) {
      float w = sW[s][c];
      const float4 x = *(const float4*)&sTt[s][rg * 4];
      acc[0] += x.x * w; acc[1] += x.y * w; acc[2] += x.z * w; acc[3] += x.w * w;
    }
  }
  const float bv = bf2[c];
#pragma unroll
  for (int u = 0; u < 4; u++) sO[rg * 4 + u][c] = acc[u] + bv;
  __syncthreads();
  const int lane = t & 63, wv = t >> 6;
  const float gv = g[lane], bbv = bb[lane];
  for (int r = wv; r < 16; r += 4) {
    const int row = row0 + r;
    float x = hV[(size_t)row * 64 + lane] + sO[r][lane];
    float s1 = x, s2 = x * x;
#pragma unroll
    for (int off = 32; off; off >>= 1) {
      s1 += __shfl_xor(s1, off, 64);
      s2 += __shfl_xor(s2, off, 64);
    }
    float m = s1 * (1.f / 64.f);
    float var = s2 * (1.f / 64.f) - m * m;
    float inv = rsqrtf(var + 1e-5f);
    float y = (x - m) * inv * gv + bbv;
    hV[(size_t)row * 64 + lane] = y * mask[row];
  }
}

// ---------------- out = hV @ W_out + b_out ----------------
__global__ __launch_bounds__(256) void k_out(const float* __restrict__ hV,
                                             const float* __restrict__ Wo,
                                             const float* __restrict__ bo,
                                             float* __restrict__ out) {
  const int t = threadIdx.x;
  const int lane = t & 63, wv = t >> 6;
  const int row = blockIdx.x * 4 + wv;
  float v = hV[(size_t)row * 64 + lane] * Wo[lane];
#pragma unroll
  for (int off = 32; off; off >>= 1) v += __shfl_xor(v, off, 64);
  if (lane == 0) out[row] = v + bo[0];
}

extern "C" void kernel_launch(void* const* d_in, const int* in_sizes, int n_in,
                              void* d_out, int out_size, void* d_ws, size_t ws_size,
                              hipStream_t stream) {
  const float* coords = (const float*)d_in[0];
  const float* nodef = (const float*)d_in[1];
  const float* mask = (const float*)d_in[2];
  const float* W_node = (const float*)d_in[3];
  const float* b_node = (const float*)d_in[4];
  const float* W_ee = (const float*)d_in[5];
  const float* g_eln = (const float*)d_in[6];
  const float* b_eln = (const float*)d_in[7];
  const float* W_ep = (const float*)d_in[8];
  const float* b_ep = (const float*)d_in[9];
  const float* WQ = (const float*)d_in[10];
  const float* bQ = (const float*)d_in[11];
  const float* WK = (const float*)d_in[12];
  const float* bK = (const float*)d_in[13];
  const float* WV = (const float*)d_in[14];
  const float* bV = (const float*)d_in[15];
  const float* WO = (const float*)d_in[16];
  const float* bO = (const float*)d_in[17];
  const float* g1 = (const float*)d_in[18];
  const float* b1 = (const float*)d_in[19];
  const float* W1 = (const float*)d_in[20];
  const float* bf1 = (const float*)d_in[21];
  const float* W2 = (const float*)d_in[22];
  const float* bf2 = (const float*)d_in[23];
  const float* g2 = (const float*)d_in[24];
  const float* b2 = (const float*)d_in[25];
  const float* W_out = (const float*)d_in[26];
  const float* b_out = (const float*)d_in[27];

  float* ws = (float*)d_ws;
  float* hV = ws;                          // 1,048,576 f
  float* Qb = hV + 1048576;                // 1,048,576 f  (Q, later upd)
  float* QW = Qb + 1048576;                // 8,388,608 f  (also aliased as Tb)
  float* Pg = QW + 8388608;                // 8,388,608 f  (also aliased as Part)
  float* qbK = Pg + 8388608;               // 65,536 f
  float* ats = qbK + 65536;                // 65,536 f
  int* Eidx = (int*)(ats + 65536);         // 491,520 i
  __half* Eln = (__half*)(Eidx + 491520);  // 7,864,320 h   (total ~93.7 MB)
  float* Tb = QW;                          // alias: lifetime disjoint from QW
  float* Part = Pg;                        // alias: k_node partials (4 x 1,048,576 f)

  k_node_part<<<512, 256, 0, stream>>>(nodef, W_node, Part);
  k_node_sum<<<1024, 256, 0, stream>>>(Part, b_node, hV);
  k_edges<<<16384, 256, 0, stream>>>(coords, mask, W_ee, g_eln, b_eln, Eidx, Eln);
  for (int l = 0; l < 4; l++) {
    k_gemm64<<<256, 256, 0, stream>>>(hV, WQ + l * 4096, bQ + l * 64, Qb);
    k_qw<<<256, 256, 0, stream>>>(Qb, WK + l * 8192, bK + l * 64, QW, qbK);
    k_attn<<<16384, 256, 0, stream>>>(Eln, Eidx, hV, mask, QW, qbK,
                                      W_ep, b_ep, Pg, ats);
    k_upd<<<2048, 256, 0, stream>>>(Pg, ats, WV + l * 8192, bV + l * 64, Qb);
    k_resln<<<1024, 256, 0, stream>>>(Qb, WO + l * 4096, bO + l * 64,
                                      g1 + l * 64, b1 + l * 64, hV);
    k_ffn1<<<1024, 256, 0, stream>>>(hV, W1 + l * 16384, bf1 + l * 256, Tb);
    k_ffn2<<<1024, 256, 0, stream>>>(Tb, W2 + l * 16384, bf2 + l * 64,
                                     g2 + l * 64, b2 + l * 64, mask, hV);
  }
  k_out<<<4096, 256, 0, stream>>>(hV, W_out, b_out, (float*)d_out);
}

// Round 5
// 903.507 us; speedup vs baseline: 1.8623x; 1.3951x over previous
//
#include <hip/hip_runtime.h>
#include <hip/hip_fp16.h>

#define L_ 2048
#define NROW 16384
#define FIN 1038

// ---------------- node embedding part: Part[split] = X[:, ks:ke] @ W[ks:ke, :] ----------------
__global__ __launch_bounds__(256) void k_node_part(const float* __restrict__ X,
                                                   const float* __restrict__ W,
                                                   float* __restrict__ Part) {
  const int rb = blockIdx.x >> 2;
  const int split = blockIdx.x & 3;
  const int kStart = split * 260;
  const int kEnd = (split == 3) ? FIN : (kStart + 260);
  const int t = threadIdx.x;
  const int row0 = rb * 128;
  __shared__ float Xs[2][16][132];
  __shared__ float Ws[2][16][64];
  const int ri = t >> 3;
  const int ci = t & 7;
  const int sxr = t >> 2;
  const int sxk = (t & 3) * 4;
  const int swr = t >> 4;
  const int swc = (t & 15) * 4;

  float acc[4][8];
#pragma unroll
  for (int u = 0; u < 4; u++)
#pragma unroll
    for (int v = 0; v < 8; v++) acc[u][v] = 0.f;

  float4 px0, px1, pwv;

#define LOADX(dst, kc, rsub)                                            \
  {                                                                     \
    const int col = (kc) + sxk;                                         \
    const float* xr = &X[(size_t)(row0 + sxr + 64 * (rsub)) * FIN];     \
    float4 v = make_float4(0.f, 0.f, 0.f, 0.f);                         \
    if (col + 4 <= kEnd) v = *(const float4*)&xr[col];                  \
    else {                                                              \
      if (col + 0 < kEnd) v.x = xr[col + 0];                            \
      if (col + 1 < kEnd) v.y = xr[col + 1];                            \
      if (col + 2 < kEnd) v.z = xr[col + 2];                            \
      if (col + 3 < kEnd) v.w = xr[col + 3];                            \
    }                                                                   \
    dst = v;                                                            \
  }
#define LOADW(dst, kc)                                                  \
  {                                                                     \
    const int j = (kc) + swr;                                           \
    dst = (j < kEnd) ? *(const float4*)&W[(size_t)j * 64 + swc]         \
                     : make_float4(0.f, 0.f, 0.f, 0.f);                 \
  }

  LOADX(px0, kStart, 0);
  LOADX(px1, kStart, 1);
  LOADW(pwv, kStart);

  int buf = 0;
  for (int kc = kStart; kc < kEnd; kc += 16) {
    Xs[buf][sxk + 0][sxr] = px0.x;
    Xs[buf][sxk + 1][sxr] = px0.y;
    Xs[buf][sxk + 2][sxr] = px0.z;
    Xs[buf][sxk + 3][sxr] = px0.w;
    Xs[buf][sxk + 0][64 + sxr] = px1.x;
    Xs[buf][sxk + 1][64 + sxr] = px1.y;
    Xs[buf][sxk + 2][64 + sxr] = px1.z;
    Xs[buf][sxk + 3][64 + sxr] = px1.w;
    *(float4*)&Ws[buf][swr][swc] = pwv;
    __syncthreads();
    const int kn = kc + 16;
    if (kn < kEnd) {
      LOADX(px0, kn, 0);
      LOADX(px1, kn, 1);
      LOADW(pwv, kn);
    }
#pragma unroll
    for (int k = 0; k < 16; k++) {
      const float4 xv = *(const float4*)&Xs[buf][k][4 * ri];
      const float4 w0 = *(const float4*)&Ws[buf][k][8 * ci];
      const float4 w1 = *(const float4*)&Ws[buf][k][8 * ci + 4];
      const float xr_[4] = {xv.x, xv.y, xv.z, xv.w};
      const float wc_[8] = {w0.x, w0.y, w0.z, w0.w, w1.x, w1.y, w1.z, w1.w};
#pragma unroll
      for (int u = 0; u < 4; u++)
#pragma unroll
        for (int v = 0; v < 8; v++) acc[u][v] += xr_[u] * wc_[v];
    }
    buf ^= 1;
  }
#undef LOADX
#undef LOADW

  float* P = Part + (size_t)split * (NROW * 64);
#pragma unroll
  for (int u = 0; u < 4; u++) {
    const int row = row0 + 4 * ri + u;
    *(float4*)&P[(size_t)row * 64 + 8 * ci] =
        make_float4(acc[u][0], acc[u][1], acc[u][2], acc[u][3]);
    *(float4*)&P[(size_t)row * 64 + 8 * ci + 4] =
        make_float4(acc[u][4], acc[u][5], acc[u][6], acc[u][7]);
  }
}

// ---------------- hV = sum of 4 partials + bias ----------------
__global__ __launch_bounds__(256) void k_node_sum(const float* __restrict__ Part,
                                                  const float* __restrict__ bias,
                                                  float* __restrict__ out) {
  const int i = (blockIdx.x * 256 + threadIdx.x) * 4;
  const float4 a = *(const float4*)&Part[i];
  const float4 b = *(const float4*)&Part[1048576 + i];
  const float4 c = *(const float4*)&Part[2 * 1048576 + i];
  const float4 d = *(const float4*)&Part[3 * 1048576 + i];
  const float4 bb = *(const float4*)&bias[i & 63];
  float4 o;
  o.x = a.x + b.x + c.x + d.x + bb.x;
  o.y = a.y + b.y + c.y + d.y + bb.y;
  o.z = a.z + b.z + c.z + d.z + bb.z;
  o.w = a.w + b.w + c.w + d.w + bb.w;
  *(float4*)&out[i] = o;
}

// ---------------- edges: distances + histogram-select top-30 + E_ln precompute ----------------
__global__ __launch_bounds__(256) void k_edges(const float* __restrict__ coords,
                                               const float* __restrict__ mask,
                                               const float* __restrict__ Wee,
                                               const float* __restrict__ geln,
                                               const float* __restrict__ beln,
                                               int* __restrict__ Eidx,
                                               __half* __restrict__ Eln) {
  const int row = blockIdx.x;
  const int b = row >> 11;
  const int t = threadIdx.x;
  const int lane = t & 63, wid = t >> 6;
  __shared__ float sredf[4];
  __shared__ unsigned int hist[2048];
  __shared__ unsigned int wtot[4];
  __shared__ int s_bin, s_need;
  __shared__ int s_lcnt, s_outcnt;
  __shared__ unsigned int s_lkey[64];
  __shared__ int s_lidx[64];
  __shared__ int s_sel[64];
  __shared__ float sD[30];
  __shared__ int sJ[30];
  __shared__ float sWee[16][16];
  __shared__ float sg[16], sb[16];
  __shared__ float sRBF[30][16];

  if (t < 256) sWee[t >> 4][t & 15] = Wee[t];
  if (t < 16) { sg[t] = geln[t]; sb[t] = beln[t]; }
  if (t == 0) { s_lcnt = 0; s_outcnt = 0; }

  const float* cb = coords + (size_t)b * (L_ * 3);
  const int i = row & (L_ - 1);
  const float cix = cb[i * 3 + 0], ciy = cb[i * 3 + 1], ciz = cb[i * 3 + 2];
  const float mi = mask[row];
  const float* mb = mask + (size_t)b * L_;
  float d[8], mj[8];
  float dmax = 0.f;
#pragma unroll
  for (int u = 0; u < 8; u++) {
    int j = t + 256 * u;
    float dx = cix - cb[j * 3 + 0];
    float dy = ciy - cb[j * 3 + 1];
    float dz = ciz - cb[j * 3 + 2];
    float dist = sqrtf(dx * dx + dy * dy + dz * dz + 1e-6f);
    d[u] = dist;
    mj[u] = mb[j];
    dmax = fmaxf(dmax, dist);
  }
#pragma unroll
  for (int off = 32; off; off >>= 1) dmax = fmaxf(dmax, __shfl_xor(dmax, off, 64));
  if (lane == 0) sredf[wid] = dmax;
#pragma unroll
  for (int q = 0; q < 8; q++) hist[t * 8 + q] = 0u;
  __syncthreads();
  dmax = fmaxf(fmaxf(sredf[0], sredf[1]), fmaxf(sredf[2], sredf[3]));
  const float scale = 1024.0f / fmaxf(dmax, 1e-20f);
  float adj[8];
  int bin[8];
#pragma unroll
  for (int u = 0; u < 8; u++) {
    adj[u] = d[u] + (1.f - mi * mj[u]) * dmax;
    int bi = (int)(adj[u] * scale);
    bin[u] = bi < 2047 ? bi : 2047;
    atomicAdd(&hist[bin[u]], 1u);
  }
  __syncthreads();
  unsigned int c[8];
  unsigned int local = 0;
#pragma unroll
  for (int q = 0; q < 8; q++) { c[q] = hist[t * 8 + q]; local += c[q]; }
  unsigned int incl = local;
#pragma unroll
  for (int off = 1; off < 64; off <<= 1) {
    unsigned int v = __shfl_up(incl, off, 64);
    if (lane >= off) incl += v;
  }
  if (lane == 63) wtot[wid] = incl;
  __syncthreads();
  unsigned int excl = incl - local;
  for (int w = 0; w < wid; w++) excl += wtot[w];
  if (excl < 30u && excl + local >= 30u) {
    unsigned int run = excl;
#pragma unroll
    for (int q = 0; q < 8; q++) {
      if (run + c[q] >= 30u) { s_bin = t * 8 + q; s_need = 30 - (int)run; break; }
      run += c[q];
    }
  }
  __syncthreads();
  const int tbin = s_bin;
  int pos[8];
#pragma unroll
  for (int u = 0; u < 8; u++) {
    pos[u] = -1;
    if (bin[u] == tbin) {
      int p = atomicAdd(&s_lcnt, 1);
      if (p < 64) { s_lkey[p] = __float_as_uint(adj[u]); s_lidx[p] = t + 256 * u; pos[u] = p; }
    }
  }
  __syncthreads();
  {
    int n = s_lcnt < 64 ? s_lcnt : 64;
    if (t < n) {
      unsigned int k0 = s_lkey[t];
      int j0 = s_lidx[t];
      int r = 0;
      for (int m = 0; m < n; m++) {
        unsigned int km = s_lkey[m];
        r += (km < k0) || (km == k0 && s_lidx[m] < j0);
      }
      s_sel[t] = (r < s_need) ? 1 : 0;
    }
  }
  __syncthreads();
#pragma unroll
  for (int u = 0; u < 8; u++) {
    bool sel = (bin[u] < tbin) || (pos[u] >= 0 && s_sel[pos[u]]);
    if (sel) {
      int o = atomicAdd(&s_outcnt, 1);
      if (o < 30) { sJ[o] = t + 256 * u; sD[o] = adj[u]; }
    }
  }
  __syncthreads();
  if (t < 30) Eidx[(size_t)row * 30 + t] = sJ[t];
  for (int o = t; o < 480; o += 256) {
    int k = o >> 4, s = o & 15;
    float mu = 2.0f + (4.0f / 3.0f) * (float)s;
    float z = (sD[k] - mu) * 0.8f;
    sRBF[k][s] = __expf(-z * z);
  }
  __syncthreads();
  if (t < 240) {
    int k = t >> 3, p = t & 7;
    int c0 = p * 2, c1 = c0 + 1;
    float e0 = 0.f, e1 = 0.f;
#pragma unroll
    for (int s = 0; s < 16; s++) {
      float r = sRBF[k][s];
      e0 += r * sWee[s][c0];
      e1 += r * sWee[s][c1];
    }
    float s1 = e0 + e1, s2 = e0 * e0 + e1 * e1;
#pragma unroll
    for (int m = 1; m < 8; m <<= 1) {
      s1 += __shfl_xor(s1, m, 64);
      s2 += __shfl_xor(s2, m, 64);
    }
    float mean = s1 * (1.f / 16.f);
    float var = s2 * (1.f / 16.f) - mean * mean;
    float inv = rsqrtf(var + 1e-5f);
    Eln[(size_t)row * 480 + k * 16 + c0] = __float2half((e0 - mean) * inv * sg[c0] + sb[c0]);
    Eln[(size_t)row * 480 + k * 16 + c1] = __float2half((e1 - mean) * inv * sg[c1] + sb[c1]);
  }
}

// ---------------- per-layer weight folding ----------------
// WKfold[l][t][c] = sum_s Wep[t][s]*WK[l][s][c] (edge rows);  bK2 = bK + bep@WK_top
// WepWV[l][t][c] = sum_s Wep[t][s]*WV[l][s][c];               bV2 = bV + bep@WV_top
__global__ __launch_bounds__(256) void k_prep(const float* __restrict__ Wep,
                                              const float* __restrict__ bep,
                                              const float* __restrict__ WK,
                                              const float* __restrict__ bK,
                                              const float* __restrict__ WV,
                                              const float* __restrict__ bV,
                                              float* __restrict__ WKfold,
                                              float* __restrict__ bK2,
                                              float* __restrict__ WepWV,
                                              float* __restrict__ bV2) {
  const int l = blockIdx.x >> 1, isV = blockIdx.x & 1;
  const float* W = (isV ? WV : WK) + (size_t)l * 8192;
  const float* bsrc = (isV ? bV : bK) + l * 64;
  float* fold = (isV ? WepWV : WKfold) + l * 1024;
  float* b2 = (isV ? bV2 : bK2) + l * 64;
  __shared__ float sW[64][64];
  __shared__ float sWep[16][64];
  const int t = threadIdx.x;
  for (int q = 0; q < 16; q++) { int i = t + 256 * q; sW[i >> 6][i & 63] = W[i]; }
  for (int q = 0; q < 4; q++)  { int i = t + 256 * q; sWep[i >> 6][i & 63] = Wep[i]; }
  __syncthreads();
  const int c = t & 63, rg = t >> 6;
  for (int r = rg; r < 16; r += 4) {
    float a = 0.f;
    for (int s = 0; s < 64; s++) a += sWep[r][s] * sW[s][c];
    fold[r * 64 + c] = a;
  }
  if (t < 64) {
    float a = bsrc[t];
    for (int s = 0; s < 64; s++) a += bep[s] * sW[s][t];
    b2[t] = a;
  }
}

// ---------------- generic 64x64 GEMM + bias (Q projection) ----------------
__global__ __launch_bounds__(256) void k_gemm64(const float* __restrict__ X,
                                                const float* __restrict__ W,
                                                const float* __restrict__ bias,
                                                float* __restrict__ out) {
  __shared__ float Xs[64][64];
  __shared__ float Ws[64][64];
  const int t = threadIdx.x;
  const int row0 = blockIdx.x * 64;
#pragma unroll
  for (int q = 0; q < 16; q++) {
    int i = t + 256 * q;
    int r = i >> 6, c = i & 63;
    Xs[r][c] = X[(size_t)(row0 + r) * 64 + c];
    Ws[r][c] = W[i];
  }
  __syncthreads();
  const int c = t & 63, rg = t >> 6;
  float acc[16];
#pragma unroll
  for (int u = 0; u < 16; u++) acc[u] = 0.f;
#pragma unroll
  for (int s0 = 0; s0 < 64; s0 += 4) {
    float w0 = Ws[s0][c], w1 = Ws[s0 + 1][c], w2 = Ws[s0 + 2][c], w3 = Ws[s0 + 3][c];
#pragma unroll
    for (int u = 0; u < 16; u++) {
      const float4 a = *(const float4*)&Xs[rg + 4 * u][s0];
      acc[u] += a.x * w0 + a.y * w1 + a.z * w2 + a.w * w3;
    }
  }
  const float bb = bias[c];
#pragma unroll
  for (int u = 0; u < 16; u++)
    out[(size_t)(row0 + rg + 4 * u) * 64 + c] = acc[u] + bb;
}

// ---------------- k_qw: node-half QW + folded edge factors + bias dot ----------------
// QWn[row][h][s64] = sum_d Q[row][h*16+d] * WK[64+s][h*16+d]
// eqw[row][h][t16] = sum_d Q[row][h*16+d] * WKfold[t][h*16+d]
// qb2[row][h]      = sum_d Q[row][h*16+d] * bK2[h*16+d]
__global__ __launch_bounds__(256) void k_qw(const float* __restrict__ Q,
                                            const float* __restrict__ WK,
                                            const float* __restrict__ WKfold,
                                            const float* __restrict__ bK2,
                                            float* __restrict__ QWn,
                                            float* __restrict__ eqw,
                                            float* __restrict__ qb2) {
  __shared__ float sQ[64 * 68];
  __shared__ float sb[64];
  const int t = threadIdx.x;
  const int row0 = blockIdx.x * 64;
  for (int q = 0; q < 16; q++) {
    int i = t + 256 * q;
    int r = i >> 6, c = i & 63;
    sQ[r * 68 + c] = Q[(size_t)(row0 + r) * 64 + c];
  }
  if (t < 64) sb[t] = bK2[t];
  const int h = t >> 6, s2 = t & 63;
  const float4 wk0 = *(const float4*)&WK[(size_t)(64 + s2) * 64 + h * 16 + 0];
  const float4 wk1 = *(const float4*)&WK[(size_t)(64 + s2) * 64 + h * 16 + 4];
  const float4 wk2 = *(const float4*)&WK[(size_t)(64 + s2) * 64 + h * 16 + 8];
  const float4 wk3 = *(const float4*)&WK[(size_t)(64 + s2) * 64 + h * 16 + 12];
  __syncthreads();
  for (int r = 0; r < 64; r++) {
    const float4 q0 = *(const float4*)&sQ[r * 68 + h * 16 + 0];
    const float4 q1 = *(const float4*)&sQ[r * 68 + h * 16 + 4];
    const float4 q2 = *(const float4*)&sQ[r * 68 + h * 16 + 8];
    const float4 q3 = *(const float4*)&sQ[r * 68 + h * 16 + 12];
    float a = q0.x * wk0.x + q0.y * wk0.y + q0.z * wk0.z + q0.w * wk0.w
            + q1.x * wk1.x + q1.y * wk1.y + q1.z * wk1.z + q1.w * wk1.w
            + q2.x * wk2.x + q2.y * wk2.y + q2.z * wk2.z + q2.w * wk2.w
            + q3.x * wk3.x + q3.y * wk3.y + q3.z * wk3.z + q3.w * wk3.w;
    QWn[(size_t)(row0 + r) * 256 + h * 64 + s2] = a;
  }
  // eqw pass: t -> (hh = t>>6, rb4 = (t>>4)&3, tt = t&15)
  {
    const int hh = t >> 6, rb4 = (t >> 4) & 3, tt = t & 15;
    const float4 wf0 = *(const float4*)&WKfold[tt * 64 + hh * 16 + 0];
    const float4 wf1 = *(const float4*)&WKfold[tt * 64 + hh * 16 + 4];
    const float4 wf2 = *(const float4*)&WKfold[tt * 64 + hh * 16 + 8];
    const float4 wf3 = *(const float4*)&WKfold[tt * 64 + hh * 16 + 12];
    for (int rr = 0; rr < 16; rr++) {
      const int r = rr * 4 + rb4;
      const float4 q0 = *(const float4*)&sQ[r * 68 + hh * 16 + 0];
      const float4 q1 = *(const float4*)&sQ[r * 68 + hh * 16 + 4];
      const float4 q2 = *(const float4*)&sQ[r * 68 + hh * 16 + 8];
      const float4 q3 = *(const float4*)&sQ[r * 68 + hh * 16 + 12];
      float a = q0.x * wf0.x + q0.y * wf0.y + q0.z * wf0.z + q0.w * wf0.w
              + q1.x * wf1.x + q1.y * wf1.y + q1.z * wf1.z + q1.w * wf1.w
              + q2.x * wf2.x + q2.y * wf2.y + q2.z * wf2.z + q2.w * wf2.w
              + q3.x * wf3.x + q3.y * wf3.y + q3.z * wf3.z + q3.w * wf3.w;
      eqw[(size_t)(row0 + r) * 64 + hh * 16 + tt] = a;
    }
  }
  // qb2 pass: t -> (r = t>>2, h2 = t&3)
  {
    const int r = t >> 2, h2 = t & 3;
    float a = 0.f;
#pragma unroll
    for (int d = 0; d < 16; d++) a += sQ[r * 68 + h2 * 16 + d] * sb[h2 * 16 + d];
    qb2[(size_t)(row0 + r) * 4 + h2] = a;
  }
}

// ---------------- per-row attention core: single barrier, per-wave per-head ----------------
__global__ __launch_bounds__(256) void k_attn(
    const __half* __restrict__ Eln, const int* __restrict__ Eidx,
    const float* __restrict__ hV, const float* __restrict__ mask,
    const float* __restrict__ QWn, const float* __restrict__ eqw,
    const float* __restrict__ qb2,
    float* __restrict__ Pg, float* __restrict__ attsum) {
  const int row = blockIdx.x;
  const int b = row >> 11;
  const int t = threadIdx.x;
  const int lane = t & 63, wid = t >> 6;
  __shared__ float sHV[30 * 65];  // stride 65: conflict-free scalar access
  __shared__ float sE[30 * 17];   // stride 17: conflict-free
  __shared__ float sQn[256];      // [h][s]
  __shared__ float swq[64];       // [h][t16]
  __shared__ float sqb2[4];
  __shared__ float smk[32];

  // ---- stage (no intra-stage dependencies) ----
  sQn[t] = QWn[(size_t)row * 256 + t];
  if (t < 64) swq[t] = eqw[(size_t)row * 64 + t];
  if (t < 4) sqb2[t] = qb2[(size_t)row * 4 + t];
  if (t < 30) smk[t] = mask[(b << 11) + Eidx[(size_t)row * 30 + t]] * mask[row];
  for (int o = t; o < 480; o += 256)
    sE[(o >> 4) * 17 + (o & 15)] = __half2float(Eln[(size_t)row * 480 + o]);
#pragma unroll
  for (int q = 0; q < 8; q++) {
    int o = t + 256 * q;
    if (o < 1920) {
      int k = o >> 6, c = o & 63;
      int j = Eidx[(size_t)row * 30 + k];
      sHV[k * 65 + c] = hV[((size_t)(b << 11) + j) * 64 + c];
    }
  }
  __syncthreads();

  // ---- per-wave: head = wid ----
  // logits: lanes 0..29 handle (k, z=0: s 0..31 / t 0..7); 30..59 handle (k, z=1)
  const int kk = (lane < 30) ? lane : (lane - 30);
  const int sbase = (lane < 30) ? 0 : 32;
  const int tbase = (lane < 30) ? 0 : 8;
  float lg = 0.f;
  if (lane < 60) {
#pragma unroll
    for (int s = 0; s < 32; s++)
      lg += sHV[kk * 65 + sbase + s] * sQn[wid * 64 + sbase + s];
#pragma unroll
    for (int tt = 0; tt < 8; tt++)
      lg += sE[kk * 17 + tbase + tt] * swq[wid * 16 + tbase + tt];
  }
  float oth = __shfl(lg, lane + 30, 64);
  float mk = (lane < 30) ? smk[lane] : 0.f;
  float lgv = (lane < 30 && mk > 0.f) ? (lg + oth + sqb2[wid]) * 0.25f
                                      : -3.402823466e38f;
  // in-wave softmax over 30
  float mx = lgv;
#pragma unroll
  for (int off = 32; off; off >>= 1) mx = fmaxf(mx, __shfl_xor(mx, off, 64));
  float e = (lane < 30) ? __expf(lgv - mx) : 0.f;
  float den = e;
#pragma unroll
  for (int off = 32; off; off >>= 1) den += __shfl_xor(den, off, 64);
  float att = e * (1.f / den) * mk;
  float ss = att;
#pragma unroll
  for (int off = 32; off; off >>= 1) ss += __shfl_xor(ss, off, 64);
  // P-node (64-wide) + eatt (16-wide) via att broadcast
  float pn = 0.f, ea = 0.f;
  for (int k2 = 0; k2 < 30; k2++) {
    float a = __shfl(att, k2, 64);
    pn += a * sHV[k2 * 65 + lane];
    float ev = sE[k2 * 17 + (lane & 15)];
    if (lane < 16) ea += a * ev;
  }
  float* pr = Pg + (size_t)row * 320 + wid * 80;
  pr[lane] = pn;
  if (lane < 16) pr[64 + lane] = ea;
  if (lane == 0) attsum[(size_t)row * 4 + wid] = ss;
}

// ---------------- upd = Pnode @ WV_bot + eatt @ WepWV + ats*bV2 ----------------
__global__ __launch_bounds__(256) void k_upd(const float* __restrict__ Pg,
                                             const float* __restrict__ ats,
                                             const float* __restrict__ WV,
                                             const float* __restrict__ WepWV,
                                             const float* __restrict__ bV2,
                                             float* __restrict__ U) {
  __shared__ float sWVb[64 * 64];
  __shared__ float sWf[16 * 64];
  __shared__ float sb[64];
  __shared__ float sP[8 * 320];
  const int t = threadIdx.x;
  const int row0 = blockIdx.x * 8;
  for (int q = 0; q < 16; q++) {
    int i = t + 256 * q;
    sWVb[i] = WV[4096 + i];  // rows 64..127
  }
  for (int q = 0; q < 4; q++) {
    int i = t + 256 * q;
    sWf[i] = WepWV[i];
  }
  if (t < 64) sb[t] = bV2[t];
  for (int q = 0; q < 10; q++) {
    int i = t + 256 * q;
    sP[i] = Pg[(size_t)row0 * 320 + i];
  }
  __syncthreads();
  const int c = t & 63, rg = t >> 6;
  const int h = c >> 4;
  const int r0 = rg * 2;
  float a0 = 0.f, a1 = 0.f;
#pragma unroll 8
  for (int s = 0; s < 64; s++) {
    float w = sWVb[s * 64 + c];
    a0 += sP[r0 * 320 + h * 80 + s] * w;
    a1 += sP[(r0 + 1) * 320 + h * 80 + s] * w;
  }
#pragma unroll
  for (int tt = 0; tt < 16; tt++) {
    float w = sWf[tt * 64 + c];
    a0 += sP[r0 * 320 + h * 80 + 64 + tt] * w;
    a1 += sP[(r0 + 1) * 320 + h * 80 + 64 + tt] * w;
  }
  const float bv = sb[c];
  const int grow = row0 + r0;
  U[(size_t)grow * 64 + c] = a0 + ats[(size_t)grow * 4 + h] * bv;
  U[(size_t)(grow + 1) * 64 + c] = a1 + ats[(size_t)(grow + 1) * 4 + h] * bv;
}

// ---------------- hV = LN(hV + U @ WO + bO) ----------------
__global__ __launch_bounds__(256) void k_resln(const float* __restrict__ U,
                                               const float* __restrict__ WO,
                                               const float* __restrict__ bO,
                                               const float* __restrict__ g,
                                               const float* __restrict__ bb,
                                               float* __restrict__ hV) {
  __shared__ float sUt[64][16];
  __shared__ float sW[64][64];
  __shared__ float sO[16][64];
  const int t = threadIdx.x;
  const int row0 = blockIdx.x * 16;
#pragma unroll
  for (int q = 0; q < 4; q++) {
    int i = t + 256 * q;
    int r = i >> 6, cc = i & 63;
    sUt[cc][r] = U[(size_t)(row0 + r) * 64 + cc];
  }
#pragma unroll
  for (int q = 0; q < 16; q++) {
    int i = t + 256 * q;
    sW[i >> 6][i & 63] = WO[i];
  }
  __syncthreads();
  const int c = t & 63, rg = t >> 6;
  float acc[4] = {0.f, 0.f, 0.f, 0.f};
#pragma unroll
  for (int s = 0; s < 64; s++) {
    float w = sW[s][c];
    const float4 x = *(const float4*)&sUt[s][rg * 4];
    acc[0] += x.x * w; acc[1] += x.y * w; acc[2] += x.z * w; acc[3] += x.w * w;
  }
  const float bv = bO[c];
#pragma unroll
  for (int u = 0; u < 4; u++) sO[rg * 4 + u][c] = acc[u] + bv;
  __syncthreads();
  const int lane = t & 63, wv = t >> 6;
  const float gv = g[lane], bbv = bb[lane];
  for (int r = wv; r < 16; r += 4) {
    const int row = row0 + r;
    float x = hV[(size_t)row * 64 + lane] + sO[r][lane];
    float s1 = x, s2 = x * x;
#pragma unroll
    for (int off = 32; off; off >>= 1) {
      s1 += __shfl_xor(s1, off, 64);
      s2 += __shfl_xor(s2, off, 64);
    }
    float m = s1 * (1.f / 64.f);
    float var = s2 * (1.f / 64.f) - m * m;
    float inv = rsqrtf(var + 1e-5f);
    hV[(size_t)row * 64 + lane] = (x - m) * inv * gv + bbv;
  }
}

// ---------------- T = relu(hV @ W1 + bf1) ----------------
__global__ __launch_bounds__(256) void k_ffn1(const float* __restrict__ X,
                                              const float* __restrict__ W1,
                                              const float* __restrict__ bf1,
                                              float* __restrict__ T) {
  __shared__ float sXt[64][16];
  __shared__ float sW[32][256];
  const int t = threadIdx.x;
  const int row0 = blockIdx.x * 16;
#pragma unroll
  for (int q = 0; q < 4; q++) {
    int i = t + 256 * q;
    int r = i >> 6, cc = i & 63;
    sXt[cc][r] = X[(size_t)(row0 + r) * 64 + cc];
  }
  float acc[16];
#pragma unroll
  for (int u = 0; u < 16; u++) acc[u] = 0.f;
  for (int kc = 0; kc < 64; kc += 32) {
    __syncthreads();
#pragma unroll
    for (int q = 0; q < 32; q++) {
      int i = t + 256 * q;
      sW[i >> 8][i & 255] = W1[(size_t)(kc + (i >> 8)) * 256 + (i & 255)];
    }
    __syncthreads();
#pragma unroll
    for (int s = 0; s < 32; s++) {
      float w = sW[s][t];
      const float4 x0 = *(const float4*)&sXt[kc + s][0];
      const float4 x1 = *(const float4*)&sXt[kc + s][4];
      const float4 x2 = *(const float4*)&sXt[kc + s][8];
      const float4 x3 = *(const float4*)&sXt[kc + s][12];
      acc[0] += x0.x * w; acc[1] += x0.y * w; acc[2] += x0.z * w; acc[3] += x0.w * w;
      acc[4] += x1.x * w; acc[5] += x1.y * w; acc[6] += x1.z * w; acc[7] += x1.w * w;
      acc[8] += x2.x * w; acc[9] += x2.y * w; acc[10] += x2.z * w; acc[11] += x2.w * w;
      acc[12] += x3.x * w; acc[13] += x3.y * w; acc[14] += x3.z * w; acc[15] += x3.w * w;
    }
  }
  const float bv = bf1[t];
#pragma unroll
  for (int r = 0; r < 16; r++)
    T[(size_t)(row0 + r) * 256 + t] = fmaxf(acc[r] + bv, 0.f);
}

// ---------------- hV = LN(hV + T @ W2 + bf2) * mask ----------------
__global__ __launch_bounds__(256) void k_ffn2(const float* __restrict__ T,
                                              const float* __restrict__ W2,
                                              const float* __restrict__ bf2,
                                              const float* __restrict__ g,
                                              const float* __restrict__ bb,
                                              const float* __restrict__ mask,
                                              float* __restrict__ hV) {
  __shared__ float sTt[64][16];
  __shared__ float sW[64][64];
  __shared__ float sO[16][64];
  const int t = threadIdx.x;
  const int row0 = blockIdx.x * 16;
  const int c = t & 63, rg = t >> 6;
  float acc[4] = {0.f, 0.f, 0.f, 0.f};
  for (int kc = 0; kc < 256; kc += 64) {
    __syncthreads();
#pragma unroll
    for (int q = 0; q < 4; q++) {
      int i = t + 256 * q;
      int r = i >> 6, cc = i & 63;
      sTt[cc][r] = T[(size_t)(row0 + r) * 256 + kc + cc];
    }
#pragma unroll
    for (int q = 0; q < 16; q++) {
      int i = t + 256 * q;
      sW[i >> 6][i & 63] = W2[(size_t)(kc + (i >> 6)) * 64 + (i & 63)];
    }
    __syncthreads();
#pragma unroll
    for (int s = 0; s < 64; s++) {
      float w = sW[s][c];
      const float4 x = *(const float4*)&sTt[s][rg * 4];
      acc[0] += x.x * w; acc[1] += x.y * w; acc[2] += x.z * w; acc[3] += x.w * w;
    }
  }
  const float bv = bf2[c];
#pragma unroll
  for (int u = 0; u < 4; u++) sO[rg * 4 + u][c] = acc[u] + bv;
  __syncthreads();
  const int lane = t & 63, wv = t >> 6;
  const float gv = g[lane], bbv = bb[lane];
  for (int r = wv; r < 16; r += 4) {
    const int row = row0 + r;
    float x = hV[(size_t)row * 64 + lane] + sO[r][lane];
    float s1 = x, s2 = x * x;
#pragma unroll
    for (int off = 32; off; off >>= 1) {
      s1 += __shfl_xor(s1, off, 64);
      s2 += __shfl_xor(s2, off, 64);
    }
    float m = s1 * (1.f / 64.f);
    float var = s2 * (1.f / 64.f) - m * m;
    float inv = rsqrtf(var + 1e-5f);
    float y = (x - m) * inv * gv + bbv;
    hV[(size_t)row * 64 + lane] = y * mask[row];
  }
}

// ---------------- out = hV @ W_out + b_out ----------------
__global__ __launch_bounds__(256) void k_out(const float* __restrict__ hV,
                                             const float* __restrict__ Wo,
                                             const float* __restrict__ bo,
                                             float* __restrict__ out) {
  const int t = threadIdx.x;
  const int lane = t & 63, wv = t >> 6;
  const int row = blockIdx.x * 4 + wv;
  float v = hV[(size_t)row * 64 + lane] * Wo[lane];
#pragma unroll
  for (int off = 32; off; off >>= 1) v += __shfl_xor(v, off, 64);
  if (lane == 0) out[row] = v + bo[0];
}

extern "C" void kernel_launch(void* const* d_in, const int* in_sizes, int n_in,
                              void* d_out, int out_size, void* d_ws, size_t ws_size,
                              hipStream_t stream) {
  const float* coords = (const float*)d_in[0];
  const float* nodef = (const float*)d_in[1];
  const float* mask = (const float*)d_in[2];
  const float* W_node = (const float*)d_in[3];
  const float* b_node = (const float*)d_in[4];
  const float* W_ee = (const float*)d_in[5];
  const float* g_eln = (const float*)d_in[6];
  const float* b_eln = (const float*)d_in[7];
  const float* W_ep = (const float*)d_in[8];
  const float* b_ep = (const float*)d_in[9];
  const float* WQ = (const float*)d_in[10];
  const float* bQ = (const float*)d_in[11];
  const float* WK = (const float*)d_in[12];
  const float* bK = (const float*)d_in[13];
  const float* WV = (const float*)d_in[14];
  const float* bV = (const float*)d_in[15];
  const float* WO = (const float*)d_in[16];
  const float* bO = (const float*)d_in[17];
  const float* g1 = (const float*)d_in[18];
  const float* b1 = (const float*)d_in[19];
  const float* W1 = (const float*)d_in[20];
  const float* bf1 = (const float*)d_in[21];
  const float* W2 = (const float*)d_in[22];
  const float* bf2 = (const float*)d_in[23];
  const float* g2 = (const float*)d_in[24];
  const float* b2 = (const float*)d_in[25];
  const float* W_out = (const float*)d_in[26];
  const float* b_out = (const float*)d_in[27];

  float* ws = (float*)d_ws;
  float* hV = ws;                           // 1,048,576 f
  float* Qb = hV + 1048576;                 // 1,048,576 f  (Q, later U)
  float* QWn = Qb + 1048576;                // 4,194,304 f  (alias Tb)
  float* eqw = QWn + 4194304;               // 1,048,576 f
  float* Pg = eqw + 1048576;                // 5,242,880 f  (alias Part: 4,194,304 f + spill into qb2? no - Part fits)
  float* qb2 = Pg + 5242880;                // 65,536 f
  float* ats = qb2 + 65536;                 // 65,536 f
  int* Eidx = (int*)(ats + 65536);          // 491,520 i
  __half* Eln = (__half*)(Eidx + 491520);   // 7,864,320 h
  float* WKfold = (float*)(Eln + 7864320);  // 4,096 f
  float* bK2 = WKfold + 4096;               // 256 f
  float* WepWV = bK2 + 256;                 // 4,096 f
  float* bV2 = WepWV + 4096;                // 256 f   (total ~69 MB)
  float* Tb = QWn;                          // alias: lifetime disjoint
  float* Part = Pg;                         // alias: k_node partials (4,194,304 f <= 5,242,880)

  k_node_part<<<512, 256, 0, stream>>>(nodef, W_node, Part);
  k_node_sum<<<1024, 256, 0, stream>>>(Part, b_node, hV);
  k_edges<<<16384, 256, 0, stream>>>(coords, mask, W_ee, g_eln, b_eln, Eidx, Eln);
  k_prep<<<8, 256, 0, stream>>>(W_ep, b_ep, WK, bK, WV, bV, WKfold, bK2, WepWV, bV2);
  for (int l = 0; l < 4; l++) {
    k_gemm64<<<256, 256, 0, stream>>>(hV, WQ + l * 4096, bQ + l * 64, Qb);
    k_qw<<<256, 256, 0, stream>>>(Qb, WK + l * 8192, WKfold + l * 1024, bK2 + l * 64,
                                  QWn, eqw, qb2);
    k_attn<<<16384, 256, 0, stream>>>(Eln, Eidx, hV, mask, QWn, eqw, qb2, Pg, ats);
    k_upd<<<2048, 256, 0, stream>>>(Pg, ats, WV + l * 8192, WepWV + l * 1024,
                                    bV2 + l * 64, Qb);
    k_resln<<<1024, 256, 0, stream>>>(Qb, WO + l * 4096, bO + l * 64,
                                      g1 + l * 64, b1 + l * 64, hV);
    k_ffn1<<<1024, 256, 0, stream>>>(hV, W1 + l * 16384, bf1 + l * 256, Tb);
    k_ffn2<<<1024, 256, 0, stream>>>(Tb, W2 + l * 16384, bf2 + l * 64,
                                     g2 + l * 64, b2 + l * 64, mask, hV);
  }
  k_out<<<4096, 256, 0, stream>>>(hV, W_out, b_out, (float*)d_out);
}